// Round 2
// baseline (16735.329 us; speedup 1.0000x reference)
//
#include <hip/hip_runtime.h>
#include <hip/hip_cooperative_groups.h>

namespace cg = cooperative_groups;

#define TT 256
#define BB 32
#define HH 512
#define EE 300
#define LL 17
#define G4 2048  /* 4*H */

using u16 = unsigned short;
using u32 = unsigned int;

// ---- bf16 helpers (RNE) ----
__device__ __forceinline__ u32 f2bf(float f) {
  u32 u = __float_as_uint(f);
  return (u + 0x7FFFu + ((u >> 16) & 1u)) >> 16;
}
__device__ __forceinline__ float bfbits2f(u32 lo) { return __uint_as_float(lo << 16); }
__device__ __forceinline__ float bflo(u32 p) { return __uint_as_float(p << 16); }
__device__ __forceinline__ float bfhi(u32 p) { return __uint_as_float(p & 0xFFFF0000u); }

// =====================================================================
// Kernel A: embedding gather + input projection for BOTH directions.
// xg[tk][g] = dot(emb[ids[tk]], w_ih[g]) + b_ih[g] + b_hh[g], stored bf16.
// tk = t*32 + b (time-major tokens). Tile 128(M) x 128(N) x 30(K), fp32.
// =====================================================================
__global__ __launch_bounds__(256) void k_input_gemm(
    const int* __restrict__ ids, const float* __restrict__ emb,
    const float* __restrict__ wih_f, const float* __restrict__ wih_b,
    const float* __restrict__ bih_f, const float* __restrict__ bhh_f,
    const float* __restrict__ bih_b, const float* __restrict__ bhh_b,
    u16* __restrict__ xgf, u16* __restrict__ xgb)
{
  __shared__ float xs[30][132];   // [k][token]  (transposed for b128 reads)
  __shared__ float wsd[30][132];  // [k][gate]
  __shared__ int idl[128];

  const int tid = threadIdx.x;
  const int mb = blockIdx.x & 63;   // 8192/128 = 64 token tiles
  const int nb = blockIdx.x >> 6;   // 4096/128 = 32 gate tiles
  const int m0 = mb * 128;
  const int n0 = nb * 128;          // global gate in [0,4096)
  const int dir = n0 >> 11;
  const int gl0 = n0 & 2047;
  const float* __restrict__ wih = dir ? wih_b : wih_f;

  if (tid < 128) {
    int tk = m0 + tid;
    idl[tid] = ids[(tk & 31) * TT + (tk >> 5)];  // ids layout [B][T]
  }
  __syncthreads();

  float acc[8][8];
#pragma unroll
  for (int i = 0; i < 8; ++i)
#pragma unroll
    for (int j = 0; j < 8; ++j) acc[i][j] = 0.f;

  const int tm = tid >> 4, tn = tid & 15;

  for (int e0 = 0; e0 < EE; e0 += 30) {
    for (int idx = tid; idx < 128 * 30; idx += 256) {
      int r = idx / 30, c = idx - r * 30;
      xs[c][r] = emb[(long)idl[r] * EE + (e0 + c)];
    }
    for (int idx = tid; idx < 128 * 30; idx += 256) {
      int r = idx / 30, c = idx - r * 30;
      wsd[c][r] = wih[(long)(gl0 + r) * EE + (e0 + c)];
    }
    __syncthreads();
#pragma unroll 2
    for (int kk = 0; kk < 30; ++kk) {
      float xv[8], wv[8];
      *(float4*)&xv[0] = *(const float4*)&xs[kk][tm * 8];
      *(float4*)&xv[4] = *(const float4*)&xs[kk][tm * 8 + 4];
      *(float4*)&wv[0] = *(const float4*)&wsd[kk][tn * 8];
      *(float4*)&wv[4] = *(const float4*)&wsd[kk][tn * 8 + 4];
#pragma unroll
      for (int i = 0; i < 8; ++i)
#pragma unroll
        for (int j = 0; j < 8; ++j)
          acc[i][j] = fmaf(xv[i], wv[j], acc[i][j]);
    }
    __syncthreads();
  }

  const float* __restrict__ bih = dir ? bih_b : bih_f;
  const float* __restrict__ bhh = dir ? bhh_b : bhh_f;
  u16* __restrict__ xg = dir ? xgb : xgf;
  const int gbase = gl0 + tn * 8;
  float bias[8];
#pragma unroll
  for (int j = 0; j < 8; ++j) bias[j] = bih[gbase + j] + bhh[gbase + j];
#pragma unroll
  for (int i = 0; i < 8; ++i) {
    int tk = m0 + tm * 8 + i;
    u32 pk[4];
#pragma unroll
    for (int jp = 0; jp < 4; ++jp) {
      u32 lo = f2bf(acc[i][2 * jp] + bias[2 * jp]);
      u32 hi = f2bf(acc[i][2 * jp + 1] + bias[2 * jp + 1]);
      pk[jp] = lo | (hi << 16);
    }
    *(uint4*)&xg[(long)tk * G4 + gbase] = make_uint4(pk[0], pk[1], pk[2], pk[3]);
  }
}

// =====================================================================
// Kernel B: cooperative BiLSTM recurrence (both directions in one grid).
// 256 blocks: dir = bx>>7, j-chunk = bx&127 (4 hidden units, all 4 gates).
// w_hh slice bf16-packed in LDS (once); h double-buffered bf16 in global,
// staged to LDS each step. 8b x 4r register tiles, 16-way k-split,
// shfl_xor(16) reduce. One grid.sync() per timestep.
// =====================================================================
__global__ __launch_bounds__(256, 1) void k_lstm(
    const u16* __restrict__ xgf, const u16* __restrict__ xgb,
    const float* __restrict__ whhf, const float* __restrict__ whhb,
    u16* __restrict__ hbuf, float* __restrict__ hsf, float* __restrict__ hsb)
{
  cg::grid_group grid = cg::this_grid();
  __shared__ u32 w_sh[16][260];   // 16 gate rows x 256 uints (2 bf16 each), padded
  __shared__ u32 h_sh[32][260];   // 32 batch x 256 uints, padded
  __shared__ float G_sh[32][17];  // gate pre-acts (hidden dot part)

  const int tid = threadIdx.x;
  const int bx = blockIdx.x;
  const int dir = bx >> 7;
  const int j0 = (bx & 127) * 4;

  const float* __restrict__ whh = dir ? whhb : whhf;
  const u16* __restrict__ xg = dir ? xgb : xgf;
  float* __restrict__ hs = dir ? hsb : hsf;
  u16* __restrict__ hbd = hbuf + dir * (2 * BB * HH);

  // stage w_hh slice: local row r = q*4+jl  ->  global row q*512 + j0 + jl
  for (int idx = tid; idx < 16 * 256; idx += 256) {
    int r = idx >> 8, c = idx & 255;
    int q = r >> 2, jl = r & 3;
    const float* wr = whh + (long)(q * HH + j0 + jl) * HH;
    u32 lo = f2bf(wr[2 * c]);
    u32 hi = f2bf(wr[2 * c + 1]);
    w_sh[r][c] = lo | (hi << 16);
  }

  const int tile = tid >> 4, ks = tid & 15;  // 16 tiles x 16 k-slices
  const int bg = tile >> 2, rg = tile & 3;   // tile = 8 batches x 4 rows (gate rg)
  const int ub = tid >> 2, ujl = tid & 3;    // update-thread mapping (tid<128)

  float c_state = 0.f;
  __syncthreads();

  for (int s = 0; s < TT; ++s) {
    const int tok = dir ? (TT - 1 - s) : s;

    // ---- stage previous h (zeros at s==0) ----
    if (s == 0) {
      for (int idx = tid; idx < 32 * 64; idx += 256)
        *(uint4*)&h_sh[idx >> 6][(idx & 63) << 2] = make_uint4(0u, 0u, 0u, 0u);
    } else {
      const uint4* __restrict__ src =
          (const uint4*)(hbd + (((s & 1) ^ 1) * (BB * HH)));
      for (int idx = tid; idx < 32 * 64; idx += 256)
        *(uint4*)&h_sh[idx >> 6][(idx & 63) << 2] = src[idx];
    }
    __syncthreads();

    // ---- dot phase: acc[bi][ri] = partial over k in {ks*4+q*64 quads} ----
    float acc[8][4];
#pragma unroll
    for (int i = 0; i < 8; ++i) {
      acc[i][0] = acc[i][1] = acc[i][2] = acc[i][3] = 0.f;
    }
#pragma unroll
    for (int q = 0; q < 8; ++q) {
      const int cu = q * 32 + ks * 2;  // uint column (covers 4 k's)
      float wf[4][4];
#pragma unroll
      for (int ri = 0; ri < 4; ++ri) {
        uint2 wq = *(const uint2*)&w_sh[rg * 4 + ri][cu];
        wf[ri][0] = bflo(wq.x); wf[ri][1] = bfhi(wq.x);
        wf[ri][2] = bflo(wq.y); wf[ri][3] = bfhi(wq.y);
      }
#pragma unroll
      for (int bi = 0; bi < 8; ++bi) {
        uint2 hq = *(const uint2*)&h_sh[bg * 8 + bi][cu];
        float h0 = bflo(hq.x), h1 = bfhi(hq.x);
        float h2 = bflo(hq.y), h3 = bfhi(hq.y);
#pragma unroll
        for (int ri = 0; ri < 4; ++ri)
          acc[bi][ri] = fmaf(h3, wf[ri][3],
                        fmaf(h2, wf[ri][2],
                        fmaf(h1, wf[ri][1],
                        fmaf(h0, wf[ri][0], acc[bi][ri]))));
      }
    }

    // ---- reduce 16 k-slices (lanes tile*16+ks are consecutive in wave) ----
#pragma unroll
    for (int m = 1; m < 16; m <<= 1) {
#pragma unroll
      for (int bi = 0; bi < 8; ++bi)
#pragma unroll
        for (int ri = 0; ri < 4; ++ri)
          acc[bi][ri] += __shfl_xor(acc[bi][ri], m, 16);
    }
    if (ks < 8) {
      const int b = bg * 8 + ks;
#pragma unroll
      for (int ri = 0; ri < 4; ++ri) G_sh[b][rg * 4 + ri] = acc[ks][ri];
    }
    __syncthreads();

    // ---- gate update: thread (b, jl) for tid<128 ----
    if (tid < 128) {
      const int b = ub, jl = ujl, j = j0 + jl;
      const long xb = (long)(tok * BB + b) * G4 + j;
      float gi = G_sh[b][jl]      + bfbits2f(xg[xb]);
      float gf = G_sh[b][4 + jl]  + bfbits2f(xg[xb + 512]);
      float gg = G_sh[b][8 + jl]  + bfbits2f(xg[xb + 1024]);
      float go = G_sh[b][12 + jl] + bfbits2f(xg[xb + 1536]);
      float i_ = 1.f / (1.f + __expf(-gi));
      float f_ = 1.f / (1.f + __expf(-gf));
      float gc = fminf(fmaxf(gg, -15.f), 15.f);
      float eg = __expf(2.f * gc);
      float g_ = (eg - 1.f) / (eg + 1.f);
      float o_ = 1.f / (1.f + __expf(-go));
      c_state = f_ * c_state + i_ * g_;
      float cc = fminf(fmaxf(c_state, -15.f), 15.f);
      float ec = __expf(2.f * cc);
      float th = (ec - 1.f) / (ec + 1.f);
      float hv = o_ * th;
      hs[(long)(tok * BB + b) * HH + j] = hv;                    // fp32 h store
      hbd[(s & 1) * (BB * HH) + b * HH + j] = (u16)f2bf(hv);     // bf16 recurrent h
    }
    __threadfence();
    grid.sync();
  }
}

// =====================================================================
// Kernel C: classifier. em[t][b][l] = b_cls[l] + hf.wcls[l,:512] + hb.wcls[l,512:]
// One block per token; 17 outputs x 4-way k-split.
// =====================================================================
__global__ __launch_bounds__(128) void k_cls(
    const float* __restrict__ hsf, const float* __restrict__ hsb,
    const float* __restrict__ wcls, const float* __restrict__ bcls,
    float* __restrict__ em)
{
  __shared__ float h_l[1024];
  __shared__ float part[17][4];
  const int tk = blockIdx.x;
  const int tid = threadIdx.x;

  const float4* pf = (const float4*)(hsf + (long)tk * HH);
  const float4* pb = (const float4*)(hsb + (long)tk * HH);
  ((float4*)h_l)[tid] = pf[tid];
  ((float4*)h_l)[128 + tid] = pb[tid];
  __syncthreads();

  if (tid < 68) {
    const int l = tid >> 2, kq = tid & 3;
    const float4* wr = (const float4*)(wcls + (long)l * 1024 + kq * 256);
    const float4* hr = (const float4*)(h_l + kq * 256);
    float sum = 0.f;
#pragma unroll 4
    for (int i = 0; i < 64; ++i) {
      float4 a = hr[i]; float4 w = wr[i];
      sum += a.x * w.x + a.y * w.y + a.z * w.z + a.w * w.w;
    }
    part[l][kq] = sum;
  }
  __syncthreads();
  if (tid < LL) {
    float v = bcls[tid] + part[tid][0] + part[tid][1] + part[tid][2] + part[tid][3];
    int t = tk >> 5, b = tk & 31;
    em[(long)t * (BB * LL) + b * LL + tid] = v;
  }
}

// =====================================================================
// Kernel D: CRF loss (torchcrf semantics, mask == all-ones).
// Single block; 544 active threads = (b, j). Stable logsumexp.
// =====================================================================
__global__ __launch_bounds__(576) void k_crf(
    const float* __restrict__ em, const int* __restrict__ labels,
    const float* __restrict__ st, const float* __restrict__ et,
    const float* __restrict__ trans, float* __restrict__ out)
{
  __shared__ float tr[LL][LL + 1];
  __shared__ float alpha[BB][LL + 1];
  __shared__ float scp[BB][LL + 1];
  __shared__ float logz[BB];
  __shared__ float score[BB];

  const int tid = threadIdx.x;
  if (tid < LL * LL) tr[tid / LL][tid % LL] = trans[tid];
  const int b = tid / LL, jj = tid - b * LL;
  const bool act = tid < BB * LL;

  if (act) alpha[b][jj] = st[jj] + em[b * LL + jj];
  __syncthreads();

  for (int t = 1; t < TT; ++t) {
    float nxt = 0.f;
    if (act) {
      const float* arow = alpha[b];
      float m = -1e30f;
#pragma unroll
      for (int i = 0; i < LL; ++i) m = fmaxf(m, arow[i] + tr[i][jj]);
      float s = 0.f;
#pragma unroll
      for (int i = 0; i < LL; ++i) s += __expf(arow[i] + tr[i][jj] - m);
      nxt = m + __logf(s) + em[(long)t * (BB * LL) + b * LL + jj];
    }
    __syncthreads();
    if (act) alpha[b][jj] = nxt;
    __syncthreads();
  }

  if (act && jj == 0) {
    float m = -1e30f;
#pragma unroll
    for (int i = 0; i < LL; ++i) m = fmaxf(m, alpha[b][i] + et[i]);
    float s = 0.f;
#pragma unroll
    for (int i = 0; i < LL; ++i) s += __expf(alpha[b][i] + et[i] - m);
    logz[b] = m + __logf(s);
  }

  // numerator: gold-path score, t-strided partials over the 17 j-threads
  if (act) {
    float p = 0.f;
    for (int t = 1 + jj; t < TT; t += LL) {
      int tp = labels[b * TT + t - 1], tc = labels[b * TT + t];
      p += tr[tp][tc] + em[(long)t * (BB * LL) + b * LL + tc];
    }
    if (jj == 0) {
      int t0 = labels[b * TT], tl = labels[b * TT + TT - 1];
      p += st[t0] + em[b * LL + t0] + et[tl];
    }
    scp[b][jj] = p;
  }
  __syncthreads();
  if (act && jj == 0) {
    float s = 0.f;
#pragma unroll
    for (int i = 0; i < LL; ++i) s += scp[b][i];
    score[b] = s;
  }
  __syncthreads();
  if (tid == 0) {
    float tot = 0.f;
    for (int bb2 = 0; bb2 < BB; ++bb2) tot += score[bb2] - logz[bb2];
    out[0] = -tot / (float)BB;
  }
}

// =====================================================================
extern "C" void kernel_launch(void* const* d_in, const int* in_sizes, int n_in,
                              void* d_out, int out_size, void* d_ws, size_t ws_size,
                              hipStream_t stream) {
  (void)in_sizes; (void)n_in; (void)out_size; (void)ws_size;

  const int* ids     = (const int*)d_in[0];
  const int* labels  = (const int*)d_in[1];
  /* d_in[2] = mask: all-ones in this problem (bool encoding ambiguous) — treated as 1 */
  const float* emb   = (const float*)d_in[3];
  const float* wih_f = (const float*)d_in[4];
  const float* whh_f = (const float*)d_in[5];
  const float* bih_f = (const float*)d_in[6];
  const float* bhh_f = (const float*)d_in[7];
  const float* wih_b = (const float*)d_in[8];
  const float* whh_b = (const float*)d_in[9];
  const float* bih_b = (const float*)d_in[10];
  const float* bhh_b = (const float*)d_in[11];
  const float* wcls  = (const float*)d_in[12];
  const float* bcls  = (const float*)d_in[13];
  const float* st    = (const float*)d_in[14];
  const float* et    = (const float*)d_in[15];
  const float* tr    = (const float*)d_in[16];

  char* ws = (char*)d_ws;
  size_t off = 0;
  auto carve = [&](size_t bytes) -> void* {
    void* p = ws + off;
    off += (bytes + 255) & ~(size_t)255;
    return p;
  };
  u16* xgf   = (u16*)carve((size_t)TT * BB * G4 * sizeof(u16));   // 33.5 MB
  u16* xgb   = (u16*)carve((size_t)TT * BB * G4 * sizeof(u16));   // 33.5 MB
  u16* hbuf  = (u16*)carve((size_t)2 * 2 * BB * HH * sizeof(u16)); // 128 KB
  float* hsf = (float*)carve((size_t)TT * BB * HH * sizeof(float)); // 16.8 MB
  float* hsb = (float*)carve((size_t)TT * BB * HH * sizeof(float)); // 16.8 MB
  float* em  = (float*)carve((size_t)TT * BB * LL * sizeof(float)); // 0.56 MB

  hipLaunchKernelGGL(k_input_gemm, dim3(64 * 32), dim3(256), 0, stream,
                     ids, emb, wih_f, wih_b, bih_f, bhh_f, bih_b, bhh_b, xgf, xgb);

  {
    void* args[] = {(void*)&xgf, (void*)&xgb, (void*)&whh_f, (void*)&whh_b,
                    (void*)&hbuf, (void*)&hsf, (void*)&hsb};
    hipLaunchCooperativeKernel((void*)k_lstm, dim3(256), dim3(256), args, 0, stream);
  }

  hipLaunchKernelGGL(k_cls, dim3(TT * BB), dim3(128), 0, stream,
                     hsf, hsb, wcls, bcls, em);

  hipLaunchKernelGGL(k_crf, dim3(1), dim3(576), 0, stream,
                     em, labels, st, et, tr, (float*)d_out);
}

// Round 3
// 4674.862 us; speedup vs baseline: 3.5799x; 3.5799x over previous
//
#include <hip/hip_runtime.h>

#define TT 256
#define BB 32
#define HH 512
#define EE 300
#define LL 17
#define G4 2048  /* 4*H */

using u16 = unsigned short;
using u32 = unsigned int;

// ---- bf16 helpers (RNE) ----
__device__ __forceinline__ u32 f2bf(float f) {
  u32 u = __float_as_uint(f);
  return (u + 0x7FFFu + ((u >> 16) & 1u)) >> 16;
}
__device__ __forceinline__ float bfbits2f(u32 lo) { return __uint_as_float(lo << 16); }
__device__ __forceinline__ float bflo(u32 p) { return __uint_as_float(p << 16); }
__device__ __forceinline__ float bfhi(u32 p) { return __uint_as_float(p & 0xFFFF0000u); }

// ---- f16 helpers ----
__device__ __forceinline__ u32 pkf16(float a, float b) {
  u16 lo = __builtin_bit_cast(u16, (_Float16)a);
  u16 hi = __builtin_bit_cast(u16, (_Float16)b);
  return (u32)lo | ((u32)hi << 16);
}
__device__ __forceinline__ float f16lo(u32 p) {
  return (float)__builtin_bit_cast(_Float16, (u16)(p & 0xFFFFu));
}
__device__ __forceinline__ float f16hi(u32 p) {
  return (float)__builtin_bit_cast(_Float16, (u16)(p >> 16));
}

#if __has_builtin(__builtin_amdgcn_fdot2)
using h2v = _Float16 __attribute__((ext_vector_type(2)));
__device__ __forceinline__ float dot2p(u32 w, u32 h, float acc) {
  return __builtin_amdgcn_fdot2(__builtin_bit_cast(h2v, w),
                                __builtin_bit_cast(h2v, h), acc, false);
}
#else
__device__ __forceinline__ float dot2p(u32 w, u32 h, float acc) {
  return fmaf(f16hi(w), f16hi(h), fmaf(f16lo(w), f16lo(h), acc));
}
#endif

__device__ __forceinline__ float dot8(uint4 w, uint4 h, float acc) {
  acc = dot2p(w.x, h.x, acc);
  acc = dot2p(w.y, h.y, acc);
  acc = dot2p(w.z, h.z, acc);
  acc = dot2p(w.w, h.w, acc);
  return acc;
}

// =====================================================================
// Kernel P: pack w_hh (both dirs) fp32 -> f16, transposed-chunked layout:
// wpk[dir][kc][g] : uint4 holding k = 8*kc .. 8*kc+7 of row g (f16x2 pairs).
// kc in [0,64), g in [0,2048). Lane-consecutive g => coalesced writes.
// =====================================================================
__global__ __launch_bounds__(256) void k_pack(
    const float* __restrict__ whhf, const float* __restrict__ whhb,
    uint4* __restrict__ wpk)
{
  int idx = blockIdx.x * 256 + threadIdx.x;   // 2*64*2048 = 262144 total
  int dir = idx >> 17;
  int rem = idx & 131071;
  int kc = rem >> 11;
  int g = rem & 2047;
  const float* w = (dir ? whhb : whhf) + (long)g * HH + kc * 8;
  uint4 o;
  o.x = pkf16(w[0], w[1]);
  o.y = pkf16(w[2], w[3]);
  o.z = pkf16(w[4], w[5]);
  o.w = pkf16(w[6], w[7]);
  wpk[idx] = o;
}

// =====================================================================
// Kernel A: embedding gather + input projection for BOTH directions.
// xg[tk][g] = dot(emb[ids[tk]], w_ih[g]) + b_ih[g] + b_hh[g], stored bf16.
// tk = t*32 + b (time-major tokens). Tile 128(M) x 128(N) x 30(K), fp32.
// =====================================================================
__global__ __launch_bounds__(256) void k_input_gemm(
    const int* __restrict__ ids, const float* __restrict__ emb,
    const float* __restrict__ wih_f, const float* __restrict__ wih_b,
    const float* __restrict__ bih_f, const float* __restrict__ bhh_f,
    const float* __restrict__ bih_b, const float* __restrict__ bhh_b,
    u16* __restrict__ xgf, u16* __restrict__ xgb)
{
  __shared__ float xs[30][132];   // [k][token]
  __shared__ float wsd[30][132];  // [k][gate]
  __shared__ int idl[128];

  const int tid = threadIdx.x;
  const int mb = blockIdx.x & 63;   // 64 token tiles
  const int nb = blockIdx.x >> 6;   // 32 gate tiles
  const int m0 = mb * 128;
  const int n0 = nb * 128;
  const int dir = n0 >> 11;
  const int gl0 = n0 & 2047;
  const float* __restrict__ wih = dir ? wih_b : wih_f;

  if (tid < 128) {
    int tk = m0 + tid;
    idl[tid] = ids[(tk & 31) * TT + (tk >> 5)];  // ids layout [B][T]
  }
  __syncthreads();

  float acc[8][8];
#pragma unroll
  for (int i = 0; i < 8; ++i)
#pragma unroll
    for (int j = 0; j < 8; ++j) acc[i][j] = 0.f;

  const int tm = tid >> 4, tn = tid & 15;

  for (int e0 = 0; e0 < EE; e0 += 30) {
    for (int idx = tid; idx < 128 * 30; idx += 256) {
      int r = idx / 30, c = idx - r * 30;
      xs[c][r] = emb[(long)idl[r] * EE + (e0 + c)];
    }
    for (int idx = tid; idx < 128 * 30; idx += 256) {
      int r = idx / 30, c = idx - r * 30;
      wsd[c][r] = wih[(long)(gl0 + r) * EE + (e0 + c)];
    }
    __syncthreads();
#pragma unroll 2
    for (int kk = 0; kk < 30; ++kk) {
      float xv[8], wv[8];
      *(float4*)&xv[0] = *(const float4*)&xs[kk][tm * 8];
      *(float4*)&xv[4] = *(const float4*)&xs[kk][tm * 8 + 4];
      *(float4*)&wv[0] = *(const float4*)&wsd[kk][tn * 8];
      *(float4*)&wv[4] = *(const float4*)&wsd[kk][tn * 8 + 4];
#pragma unroll
      for (int i = 0; i < 8; ++i)
#pragma unroll
        for (int j = 0; j < 8; ++j)
          acc[i][j] = fmaf(xv[i], wv[j], acc[i][j]);
    }
    __syncthreads();
  }

  const float* __restrict__ bih = dir ? bih_b : bih_f;
  const float* __restrict__ bhh = dir ? bhh_b : bhh_f;
  u16* __restrict__ xg = dir ? xgb : xgf;
  const int gbase = gl0 + tn * 8;
  float bias[8];
#pragma unroll
  for (int j = 0; j < 8; ++j) bias[j] = bih[gbase + j] + bhh[gbase + j];
#pragma unroll
  for (int i = 0; i < 8; ++i) {
    int tk = m0 + tm * 8 + i;
    u32 pk[4];
#pragma unroll
    for (int jp = 0; jp < 4; ++jp) {
      u32 lo = f2bf(acc[i][2 * jp] + bias[2 * jp]);
      u32 hi = f2bf(acc[i][2 * jp + 1] + bias[2 * jp + 1]);
      pk[jp] = lo | (hi << 16);
    }
    *(uint4*)&xg[(long)tk * G4 + gbase] = make_uint4(pk[0], pk[1], pk[2], pk[3]);
  }
}

// =====================================================================
// Kernel B: BiLSTM recurrence, batch-split, ZERO cross-block sync.
// 64 blocks = 2 dir x 32 batch; 1024 threads. Each block owns one
// (dir,batch) recurrence end-to-end: h lives in LDS, c in registers
// (thread tid<512 holds c[j=tid]). Per step: stream w_hh (f16, 2MB)
// from L2 with coalesced dwordx4, v_dot2 f32-accum matvec, gate update.
// Thread t computes gate rows t and t+1024.
// =====================================================================
__global__ __launch_bounds__(1024, 1) void k_lstm2(
    const u16* __restrict__ xgf, const u16* __restrict__ xgb,
    const uint4* __restrict__ wpk,
    u16* __restrict__ hsf, u16* __restrict__ hsb)
{
  __shared__ uint4 h4[64];     // 512 h values, f16x2-packed
  __shared__ float yg[2048];   // hidden-dot pre-acts

  const int tid = threadIdx.x;
  const int dir = blockIdx.x >> 5;
  const int b = blockIdx.x & 31;

  const u16* __restrict__ xg = dir ? xgb : xgf;
  u16* __restrict__ hs = dir ? hsb : hsf;
  const uint4* __restrict__ wp = wpk + (long)dir * (64 * 2048);

  const int g0 = tid, g1 = tid + 1024;

  if (tid < 64) h4[tid] = make_uint4(0u, 0u, 0u, 0u);
  float c_state = 0.f;
  __syncthreads();

  for (int s = 0; s < TT; ++s) {
    const int tok = dir ? (TT - 1 - s) : s;

    // prefetch this step's xg for the update phase (hidden under the dot)
    u32 x0 = 0, x1 = 0, x2 = 0, x3 = 0;
    if (tid < HH) {
      const u16* xb = xg + ((long)(tok * BB + b) << 11);
      x0 = xb[tid];
      x1 = xb[tid + 512];
      x2 = xb[tid + 1024];
      x3 = xb[tid + 1536];
    }

    // ---- matvec: y[g] = sum_k W[g][k] * h[k], f16 inputs, f32 accum ----
    float a0 = 0.f, a1 = 0.f;
#pragma unroll 4
    for (int kk = 0; kk < 64; ++kk) {
      uint4 hh = h4[kk];                    // wave-uniform -> LDS broadcast
      uint4 w0 = wp[(long)kk * 2048 + g0];  // lane-consecutive -> coalesced
      uint4 w1 = wp[(long)kk * 2048 + g1];
      a0 = dot8(w0, hh, a0);
      a1 = dot8(w1, hh, a1);
    }
    yg[g0] = a0;
    yg[g1] = a1;
    __syncthreads();

    // ---- gate update: thread j < 512 ----
    if (tid < HH) {
      float gi = yg[tid] + bfbits2f(x0);
      float gf = yg[tid + 512] + bfbits2f(x1);
      float gg = yg[tid + 1024] + bfbits2f(x2);
      float go = yg[tid + 1536] + bfbits2f(x3);
      float i_ = 1.f / (1.f + __expf(-gi));
      float f_ = 1.f / (1.f + __expf(-gf));
      float gc = fminf(fmaxf(gg, -15.f), 15.f);
      float eg = __expf(2.f * gc);
      float g_ = (eg - 1.f) / (eg + 1.f);
      float o_ = 1.f / (1.f + __expf(-go));
      c_state = f_ * c_state + i_ * g_;
      float cc = fminf(fmaxf(c_state, -15.f), 15.f);
      float ec = __expf(2.f * cc);
      float th = (ec - 1.f) / (ec + 1.f);
      float hv = o_ * th;
      hs[((long)(tok * BB + b) << 9) + tid] = (u16)f2bf(hv);  // bf16 h out
      ((u16*)h4)[tid] = __builtin_bit_cast(u16, (_Float16)hv);  // f16 recurrent h
    }
    __syncthreads();
  }
}

// =====================================================================
// Kernel C: classifier. em[t][b][l] = b_cls[l] + hf.wcls[l,:512] + hb.wcls[l,512:]
// One block per token; h inputs are bf16. 17 outputs x 4-way k-split.
// =====================================================================
__global__ __launch_bounds__(128) void k_cls(
    const u16* __restrict__ hsf, const u16* __restrict__ hsb,
    const float* __restrict__ wcls, const float* __restrict__ bcls,
    float* __restrict__ em)
{
  __shared__ float h_l[1024];
  __shared__ float part[17][4];
  const int tk = blockIdx.x;
  const int tid = threadIdx.x;

  {
    uint2 vf = ((const uint2*)(hsf + (long)tk * HH))[tid];  // 4 bf16
    uint2 vb = ((const uint2*)(hsb + (long)tk * HH))[tid];
    h_l[4 * tid + 0] = bflo(vf.x); h_l[4 * tid + 1] = bfhi(vf.x);
    h_l[4 * tid + 2] = bflo(vf.y); h_l[4 * tid + 3] = bfhi(vf.y);
    h_l[512 + 4 * tid + 0] = bflo(vb.x); h_l[512 + 4 * tid + 1] = bfhi(vb.x);
    h_l[512 + 4 * tid + 2] = bflo(vb.y); h_l[512 + 4 * tid + 3] = bfhi(vb.y);
  }
  __syncthreads();

  if (tid < 68) {
    const int l = tid >> 2, kq = tid & 3;
    const float4* wr = (const float4*)(wcls + (long)l * 1024 + kq * 256);
    const float4* hr = (const float4*)(h_l + kq * 256);
    float sum = 0.f;
#pragma unroll 4
    for (int i = 0; i < 64; ++i) {
      float4 a = hr[i]; float4 w = wr[i];
      sum += a.x * w.x + a.y * w.y + a.z * w.z + a.w * w.w;
    }
    part[l][kq] = sum;
  }
  __syncthreads();
  if (tid < LL) {
    float v = bcls[tid] + part[tid][0] + part[tid][1] + part[tid][2] + part[tid][3];
    int t = tk >> 5, b = tk & 31;
    em[(long)t * (BB * LL) + b * LL + tid] = v;
  }
}

// =====================================================================
// Kernel D: CRF loss (torchcrf semantics, mask == all-ones).
// Single block; 544 active threads = (b, j). Stable logsumexp.
// =====================================================================
__global__ __launch_bounds__(576) void k_crf(
    const float* __restrict__ em, const int* __restrict__ labels,
    const float* __restrict__ st, const float* __restrict__ et,
    const float* __restrict__ trans, float* __restrict__ out)
{
  __shared__ float tr[LL][LL + 1];
  __shared__ float alpha[BB][LL + 1];
  __shared__ float scp[BB][LL + 1];
  __shared__ float logz[BB];
  __shared__ float score[BB];

  const int tid = threadIdx.x;
  if (tid < LL * LL) tr[tid / LL][tid % LL] = trans[tid];
  const int b = tid / LL, jj = tid - b * LL;
  const bool act = tid < BB * LL;

  if (act) alpha[b][jj] = st[jj] + em[b * LL + jj];
  __syncthreads();

  for (int t = 1; t < TT; ++t) {
    float nxt = 0.f;
    if (act) {
      const float* arow = alpha[b];
      float m = -1e30f;
#pragma unroll
      for (int i = 0; i < LL; ++i) m = fmaxf(m, arow[i] + tr[i][jj]);
      float s = 0.f;
#pragma unroll
      for (int i = 0; i < LL; ++i) s += __expf(arow[i] + tr[i][jj] - m);
      nxt = m + __logf(s) + em[(long)t * (BB * LL) + b * LL + jj];
    }
    __syncthreads();
    if (act) alpha[b][jj] = nxt;
    __syncthreads();
  }

  if (act && jj == 0) {
    float m = -1e30f;
#pragma unroll
    for (int i = 0; i < LL; ++i) m = fmaxf(m, alpha[b][i] + et[i]);
    float s = 0.f;
#pragma unroll
    for (int i = 0; i < LL; ++i) s += __expf(alpha[b][i] + et[i] - m);
    logz[b] = m + __logf(s);
  }

  if (act) {
    float p = 0.f;
    for (int t = 1 + jj; t < TT; t += LL) {
      int tp = labels[b * TT + t - 1], tc = labels[b * TT + t];
      p += tr[tp][tc] + em[(long)t * (BB * LL) + b * LL + tc];
    }
    if (jj == 0) {
      int t0 = labels[b * TT], tl = labels[b * TT + TT - 1];
      p += st[t0] + em[b * LL + t0] + et[tl];
    }
    scp[b][jj] = p;
  }
  __syncthreads();
  if (act && jj == 0) {
    float s = 0.f;
#pragma unroll
    for (int i = 0; i < LL; ++i) s += scp[b][i];
    score[b] = s;
  }
  __syncthreads();
  if (tid == 0) {
    float tot = 0.f;
    for (int bb2 = 0; bb2 < BB; ++bb2) tot += score[bb2] - logz[bb2];
    out[0] = -tot / (float)BB;
  }
}

// =====================================================================
extern "C" void kernel_launch(void* const* d_in, const int* in_sizes, int n_in,
                              void* d_out, int out_size, void* d_ws, size_t ws_size,
                              hipStream_t stream) {
  (void)in_sizes; (void)n_in; (void)out_size; (void)ws_size;

  const int* ids     = (const int*)d_in[0];
  const int* labels  = (const int*)d_in[1];
  /* d_in[2] = mask: all-ones in this problem — treated as 1 */
  const float* emb   = (const float*)d_in[3];
  const float* wih_f = (const float*)d_in[4];
  const float* whh_f = (const float*)d_in[5];
  const float* bih_f = (const float*)d_in[6];
  const float* bhh_f = (const float*)d_in[7];
  const float* wih_b = (const float*)d_in[8];
  const float* whh_b = (const float*)d_in[9];
  const float* bih_b = (const float*)d_in[10];
  const float* bhh_b = (const float*)d_in[11];
  const float* wcls  = (const float*)d_in[12];
  const float* bcls  = (const float*)d_in[13];
  const float* st    = (const float*)d_in[14];
  const float* et    = (const float*)d_in[15];
  const float* tr    = (const float*)d_in[16];

  char* ws = (char*)d_ws;
  size_t off = 0;
  auto carve = [&](size_t bytes) -> void* {
    void* p = ws + off;
    off += (bytes + 255) & ~(size_t)255;
    return p;
  };
  u16* xgf   = (u16*)carve((size_t)TT * BB * G4 * sizeof(u16));    // 33.5 MB
  u16* xgb   = (u16*)carve((size_t)TT * BB * G4 * sizeof(u16));    // 33.5 MB
  uint4* wpk = (uint4*)carve((size_t)2 * 64 * 2048 * sizeof(uint4)); // 4.2 MB
  u16* hsf   = (u16*)carve((size_t)TT * BB * HH * sizeof(u16));    // 8.4 MB
  u16* hsb   = (u16*)carve((size_t)TT * BB * HH * sizeof(u16));    // 8.4 MB
  float* em  = (float*)carve((size_t)TT * BB * LL * sizeof(float)); // 0.56 MB

  hipLaunchKernelGGL(k_pack, dim3(1024), dim3(256), 0, stream, whh_f, whh_b, wpk);

  hipLaunchKernelGGL(k_input_gemm, dim3(64 * 32), dim3(256), 0, stream,
                     ids, emb, wih_f, wih_b, bih_f, bhh_f, bih_b, bhh_b, xgf, xgb);

  hipLaunchKernelGGL(k_lstm2, dim3(64), dim3(1024), 0, stream,
                     xgf, xgb, wpk, hsf, hsb);

  hipLaunchKernelGGL(k_cls, dim3(TT * BB), dim3(128), 0, stream,
                     hsf, hsb, wcls, bcls, em);

  hipLaunchKernelGGL(k_crf, dim3(1), dim3(576), 0, stream,
                     em, labels, st, et, tr, (float*)d_out);
}

// Round 4
// 2501.026 us; speedup vs baseline: 6.6914x; 1.8692x over previous
//
#include <hip/hip_runtime.h>

#define TT 256
#define BB 32
#define HH 512
#define EE 300
#define LL 17
#define G4 2048  /* 4*H */

#define JS 16   /* j-split blocks per (dir,batch-group) */
#define BGN 8   /* batch groups */
#define BGS 4   /* batches per group */

using u16 = unsigned short;
using u32 = unsigned int;

// ---- bf16 helpers (RNE) ----
__device__ __forceinline__ u32 f2bf(float f) {
  u32 u = __float_as_uint(f);
  return (u + 0x7FFFu + ((u >> 16) & 1u)) >> 16;
}
__device__ __forceinline__ float bfbits2f(u32 lo) { return __uint_as_float(lo << 16); }
__device__ __forceinline__ float bflo(u32 p) { return __uint_as_float(p << 16); }
__device__ __forceinline__ float bfhi(u32 p) { return __uint_as_float(p & 0xFFFF0000u); }

// ---- f16 helpers ----
__device__ __forceinline__ u32 pkf16(float a, float b) {
  u16 lo = __builtin_bit_cast(u16, (_Float16)a);
  u16 hi = __builtin_bit_cast(u16, (_Float16)b);
  return (u32)lo | ((u32)hi << 16);
}
__device__ __forceinline__ float f16lo(u32 p) {
  return (float)__builtin_bit_cast(_Float16, (u16)(p & 0xFFFFu));
}
__device__ __forceinline__ float f16hi(u32 p) {
  return (float)__builtin_bit_cast(_Float16, (u16)(p >> 16));
}

#if __has_builtin(__builtin_amdgcn_fdot2)
using h2v = _Float16 __attribute__((ext_vector_type(2)));
__device__ __forceinline__ float dot2p(u32 w, u32 h, float acc) {
  return __builtin_amdgcn_fdot2(__builtin_bit_cast(h2v, w),
                                __builtin_bit_cast(h2v, h), acc, false);
}
#else
__device__ __forceinline__ float dot2p(u32 w, u32 h, float acc) {
  return fmaf(f16hi(w), f16hi(h), fmaf(f16lo(w), f16lo(h), acc));
}
#endif

#define AQ __ATOMIC_ACQUIRE
#define RL __ATOMIC_RELEASE
#define RX __ATOMIC_RELAXED
#define SCA __HIP_MEMORY_SCOPE_AGENT

// =====================================================================
// Kernel Z: zero the h-exchange buffer + step flags (every call, so graph
// replays are deterministic).
// =====================================================================
__global__ __launch_bounds__(256) void k_zero(u32* __restrict__ hx,
                                              u32* __restrict__ flags) {
  int i = blockIdx.x * 256 + threadIdx.x;
  if (i < 2 * BGN * BGS * 256) hx[i] = 0;
  if (i < 2 * BGN * JS) flags[i] = 0;
}

// =====================================================================
// Kernel P: pack w_hh fp32 -> f16 pairs in the per-thread register layout
// of k_lstm3: wreg[dir][js][i 0..128][tid 0..256], where thread tid =
// (khalf<<7)|gl holds W[row(gl,js)][khalf*256 + 2i .. +1].
// row(gl,js) = (gl>>5)*512 + js*32 + (gl&31).
// =====================================================================
__global__ __launch_bounds__(256) void k_pack2(
    const float* __restrict__ whhf, const float* __restrict__ whhb,
    u32* __restrict__ wreg)
{
  int idx = blockIdx.x * 256 + threadIdx.x;  // 2*16*128*256 = 1,048,576
  int tid2 = idx & 255;
  int i = (idx >> 8) & 127;
  int js = (idx >> 15) & 15;
  int dir = idx >> 19;
  int gl = tid2 & 127, kh = tid2 >> 7;
  int grow = (gl >> 5) * 512 + js * 32 + (gl & 31);
  int k = kh * 256 + 2 * i;
  const float* w = (dir ? whhb : whhf) + (long)grow * HH + k;
  wreg[idx] = pkf16(w[0], w[1]);
}

// =====================================================================
// Kernel A: embedding gather + input projection for BOTH directions.
// xg[tk][g] = dot(emb[ids[tk]], w_ih[g]) + b_ih[g] + b_hh[g], stored bf16.
// =====================================================================
__global__ __launch_bounds__(256) void k_input_gemm(
    const int* __restrict__ ids, const float* __restrict__ emb,
    const float* __restrict__ wih_f, const float* __restrict__ wih_b,
    const float* __restrict__ bih_f, const float* __restrict__ bhh_f,
    const float* __restrict__ bih_b, const float* __restrict__ bhh_b,
    u16* __restrict__ xgf, u16* __restrict__ xgb)
{
  __shared__ float xs[30][132];
  __shared__ float wsd[30][132];
  __shared__ int idl[128];

  const int tid = threadIdx.x;
  const int mb = blockIdx.x & 63;
  const int nb = blockIdx.x >> 6;
  const int m0 = mb * 128;
  const int n0 = nb * 128;
  const int dir = n0 >> 11;
  const int gl0 = n0 & 2047;
  const float* __restrict__ wih = dir ? wih_b : wih_f;

  if (tid < 128) {
    int tk = m0 + tid;
    idl[tid] = ids[(tk & 31) * TT + (tk >> 5)];
  }
  __syncthreads();

  float acc[8][8];
#pragma unroll
  for (int i = 0; i < 8; ++i)
#pragma unroll
    for (int j = 0; j < 8; ++j) acc[i][j] = 0.f;

  const int tm = tid >> 4, tn = tid & 15;

  for (int e0 = 0; e0 < EE; e0 += 30) {
    for (int idx = tid; idx < 128 * 30; idx += 256) {
      int r = idx / 30, c = idx - r * 30;
      xs[c][r] = emb[(long)idl[r] * EE + (e0 + c)];
    }
    for (int idx = tid; idx < 128 * 30; idx += 256) {
      int r = idx / 30, c = idx - r * 30;
      wsd[c][r] = wih[(long)(gl0 + r) * EE + (e0 + c)];
    }
    __syncthreads();
#pragma unroll 2
    for (int kk = 0; kk < 30; ++kk) {
      float xv[8], wv[8];
      *(float4*)&xv[0] = *(const float4*)&xs[kk][tm * 8];
      *(float4*)&xv[4] = *(const float4*)&xs[kk][tm * 8 + 4];
      *(float4*)&wv[0] = *(const float4*)&wsd[kk][tn * 8];
      *(float4*)&wv[4] = *(const float4*)&wsd[kk][tn * 8 + 4];
#pragma unroll
      for (int i = 0; i < 8; ++i)
#pragma unroll
        for (int j = 0; j < 8; ++j)
          acc[i][j] = fmaf(xv[i], wv[j], acc[i][j]);
    }
    __syncthreads();
  }

  const float* __restrict__ bih = dir ? bih_b : bih_f;
  const float* __restrict__ bhh = dir ? bhh_b : bhh_f;
  u16* __restrict__ xg = dir ? xgb : xgf;
  const int gbase = gl0 + tn * 8;
  float bias[8];
#pragma unroll
  for (int j = 0; j < 8; ++j) bias[j] = bih[gbase + j] + bhh[gbase + j];
#pragma unroll
  for (int i = 0; i < 8; ++i) {
    int tk = m0 + tm * 8 + i;
    u32 pk[4];
#pragma unroll
    for (int jp = 0; jp < 4; ++jp) {
      u32 lo = f2bf(acc[i][2 * jp] + bias[2 * jp]);
      u32 hi = f2bf(acc[i][2 * jp + 1] + bias[2 * jp + 1]);
      pk[jp] = lo | (hi << 16);
    }
    *(uint4*)&xg[(long)tk * G4 + gbase] = make_uint4(pk[0], pk[1], pk[2], pk[3]);
  }
}

// =====================================================================
// Kernel B: BiLSTM recurrence — register-resident weights.
// 256 blocks = 2 dir x 8 bg x 16 js, 256 threads, cooperative.
// Thread (gl,kh) holds W[row][kh-half] as 128 u32 f16-pairs in VGPRs.
// Per step: h broadcast from LDS (uniform ds_read_b128) x v_dot2 matvec;
// y halves summed via LDS; threads<128 update c,h for (jl,bl);
// h exchanged among the 16 js-siblings via L2-bypass (agent) atomics with
// a release-flag / relaxed-spin+acquire protocol. No weight re-reads,
// no L2 writeback storms.
// =====================================================================
__global__ __launch_bounds__(256, 1) void k_lstm3(
    const u16* __restrict__ xgf, const u16* __restrict__ xgb,
    const u32* __restrict__ wreg,
    u32* __restrict__ hx, u32* __restrict__ flags,
    u32* __restrict__ hsf32, u32* __restrict__ hsb32)
{
  __shared__ uint4 h4[256];                       // h[b0..b3] f16x2 per k-pair
  __shared__ __align__(16) float y_sh[2][128][4]; // [khalf][g_local][b]

  const int tid = threadIdx.x;
  const int bx = blockIdx.x;
  const int dir = bx >> 7;          // 128 blocks per dir
  const int rem = bx & 127;
  const int bg = rem >> 4;          // 8 groups
  const int js = rem & 15;          // 16 j-slices
  const int grp = dir * BGN + bg;

  const u16* __restrict__ xg = dir ? xgb : xgf;
  u32* __restrict__ hs32 = dir ? hsb32 : hsf32;

  const int gl = tid & 127, kh = tid >> 7;
  const int jl = tid & 31, bl = (tid >> 5) & 3;   // update mapping (tid<128)

  // ---- load persistent weight registers (coalesced per i) ----
  u32 warr[128];
  {
    const u32* wp = wreg + ((long)(dir * JS + js) * 128) * 256 + tid;
#pragma unroll
    for (int i = 0; i < 128; ++i) warr[i] = wp[(long)i * 256];
  }

  float c_state = 0.f;

  for (int s = 0; s < TT; ++s) {
    const int tok = dir ? (TT - 1 - s) : s;

    // ---- issue xg loads early (independent of h) ----
    u32 xq0 = 0, xq1 = 0, xq2 = 0, xq3 = 0;
    if (tid < 128) {
      const u16* xb = xg + ((long)(tok * BB + bg * BGS + bl) << 11) + js * 32 + jl;
      xq0 = xb[0]; xq1 = xb[512]; xq2 = xb[1024]; xq3 = xb[1536];
    }

    // ---- acquire previous h ----
    if (s == 0) {
      h4[tid] = make_uint4(0u, 0u, 0u, 0u);
    } else {
      if (tid < JS) {
        u32* fp = flags + grp * JS + tid;
        while (__hip_atomic_load(fp, RX, SCA) < (u32)s)
          __builtin_amdgcn_s_sleep(1);
        (void)__hip_atomic_load(fp, AQ, SCA);
      }
      __syncthreads();
      const u32* hxg = hx + grp * 1024;
      u32 b0 = __hip_atomic_load(hxg + tid, RX, SCA);
      u32 b1 = __hip_atomic_load(hxg + 256 + tid, RX, SCA);
      u32 b2 = __hip_atomic_load(hxg + 512 + tid, RX, SCA);
      u32 b3 = __hip_atomic_load(hxg + 768 + tid, RX, SCA);
      h4[tid] = make_uint4(b0, b1, b2, b3);
    }
    __syncthreads();

    // ---- matvec: acc_b = sum over this thread's k-half ----
    float a0 = 0.f, a1 = 0.f, a2 = 0.f, a3 = 0.f;
    {
      const uint4* hb = h4 + kh * 128;
#pragma unroll
      for (int i = 0; i < 128; ++i) {
        uint4 hh = hb[i];          // wave-uniform address -> LDS broadcast
        u32 w = warr[i];
        a0 = dot2p(w, hh.x, a0);
        a1 = dot2p(w, hh.y, a1);
        a2 = dot2p(w, hh.z, a2);
        a3 = dot2p(w, hh.w, a3);
      }
    }
    *(float4*)&y_sh[kh][gl][0] = make_float4(a0, a1, a2, a3);
    __syncthreads();

    // ---- gate update: thread (jl, bl), tid<128 ----
    float hv = 0.f;
    if (tid < 128) {
      float y0 = y_sh[0][jl][bl]       + y_sh[1][jl][bl]       + bfbits2f(xq0);
      float y1 = y_sh[0][32 + jl][bl]  + y_sh[1][32 + jl][bl]  + bfbits2f(xq1);
      float y2 = y_sh[0][64 + jl][bl]  + y_sh[1][64 + jl][bl]  + bfbits2f(xq2);
      float y3 = y_sh[0][96 + jl][bl]  + y_sh[1][96 + jl][bl]  + bfbits2f(xq3);
      float i_ = 1.f / (1.f + __expf(-y0));
      float f_ = 1.f / (1.f + __expf(-y1));
      float gc = fminf(fmaxf(y2, -15.f), 15.f);
      float eg = __expf(2.f * gc);
      float g_ = (eg - 1.f) / (eg + 1.f);
      float o_ = 1.f / (1.f + __expf(-y3));
      c_state = f_ * c_state + i_ * g_;
      float cc = fminf(fmaxf(c_state, -15.f), 15.f);
      float ec = __expf(2.f * cc);
      float th = (ec - 1.f) / (ec + 1.f);
      hv = o_ * th;
    }
    float hnb = __shfl_down(hv, 1);
    if (tid < 128 && !(jl & 1)) {
      u32 hp = pkf16(hv, hnb);
      int jp = js * 16 + (jl >> 1);
      __hip_atomic_store(hs32 + ((long)(tok * BB + bg * BGS + bl) << 8) + jp,
                         hp, RX, SCA);
      __hip_atomic_store(hx + grp * 1024 + bl * 256 + jp, hp, RX, SCA);
    }
    __syncthreads();   // drains vmcnt for all waves before publishing
    if (tid == 0)
      __hip_atomic_store(flags + grp * JS + js, (u32)(s + 1), RL, SCA);
  }
}

// =====================================================================
// Kernel C: classifier. h inputs are f16-packed u32.
// =====================================================================
__global__ __launch_bounds__(128) void k_cls(
    const u32* __restrict__ hsf32, const u32* __restrict__ hsb32,
    const float* __restrict__ wcls, const float* __restrict__ bcls,
    float* __restrict__ em)
{
  __shared__ float h_l[1024];
  __shared__ float part[17][4];
  const int tk = blockIdx.x;
  const int tid = threadIdx.x;

  {
    uint2 vf = ((const uint2*)(hsf32 + (long)tk * 256))[tid];  // 4 f16
    uint2 vb = ((const uint2*)(hsb32 + (long)tk * 256))[tid];
    h_l[4 * tid + 0] = f16lo(vf.x); h_l[4 * tid + 1] = f16hi(vf.x);
    h_l[4 * tid + 2] = f16lo(vf.y); h_l[4 * tid + 3] = f16hi(vf.y);
    h_l[512 + 4 * tid + 0] = f16lo(vb.x); h_l[512 + 4 * tid + 1] = f16hi(vb.x);
    h_l[512 + 4 * tid + 2] = f16lo(vb.y); h_l[512 + 4 * tid + 3] = f16hi(vb.y);
  }
  __syncthreads();

  if (tid < 68) {
    const int l = tid >> 2, kq = tid & 3;
    const float4* wr = (const float4*)(wcls + (long)l * 1024 + kq * 256);
    const float4* hr = (const float4*)(h_l + kq * 256);
    float sum = 0.f;
#pragma unroll 4
    for (int i = 0; i < 64; ++i) {
      float4 a = hr[i]; float4 w = wr[i];
      sum += a.x * w.x + a.y * w.y + a.z * w.z + a.w * w.w;
    }
    part[l][kq] = sum;
  }
  __syncthreads();
  if (tid < LL) {
    float v = bcls[tid] + part[tid][0] + part[tid][1] + part[tid][2] + part[tid][3];
    int t = tk >> 5, b = tk & 31;
    em[(long)t * (BB * LL) + b * LL + tid] = v;
  }
}

// =====================================================================
// Kernel D: CRF loss (torchcrf semantics, mask == all-ones).
// =====================================================================
__global__ __launch_bounds__(576) void k_crf(
    const float* __restrict__ em, const int* __restrict__ labels,
    const float* __restrict__ st, const float* __restrict__ et,
    const float* __restrict__ trans, float* __restrict__ out)
{
  __shared__ float tr[LL][LL + 1];
  __shared__ float alpha[BB][LL + 1];
  __shared__ float scp[BB][LL + 1];
  __shared__ float logz[BB];
  __shared__ float score[BB];

  const int tid = threadIdx.x;
  if (tid < LL * LL) tr[tid / LL][tid % LL] = trans[tid];
  const int b = tid / LL, jj = tid - b * LL;
  const bool act = tid < BB * LL;

  if (act) alpha[b][jj] = st[jj] + em[b * LL + jj];
  __syncthreads();

  for (int t = 1; t < TT; ++t) {
    float nxt = 0.f;
    if (act) {
      const float* arow = alpha[b];
      float m = -1e30f;
#pragma unroll
      for (int i = 0; i < LL; ++i) m = fmaxf(m, arow[i] + tr[i][jj]);
      float s = 0.f;
#pragma unroll
      for (int i = 0; i < LL; ++i) s += __expf(arow[i] + tr[i][jj] - m);
      nxt = m + __logf(s) + em[(long)t * (BB * LL) + b * LL + jj];
    }
    __syncthreads();
    if (act) alpha[b][jj] = nxt;
    __syncthreads();
  }

  if (act && jj == 0) {
    float m = -1e30f;
#pragma unroll
    for (int i = 0; i < LL; ++i) m = fmaxf(m, alpha[b][i] + et[i]);
    float s = 0.f;
#pragma unroll
    for (int i = 0; i < LL; ++i) s += __expf(alpha[b][i] + et[i] - m);
    logz[b] = m + __logf(s);
  }

  if (act) {
    float p = 0.f;
    for (int t = 1 + jj; t < TT; t += LL) {
      int tp = labels[b * TT + t - 1], tc = labels[b * TT + t];
      p += tr[tp][tc] + em[(long)t * (BB * LL) + b * LL + tc];
    }
    if (jj == 0) {
      int t0 = labels[b * TT], tl = labels[b * TT + TT - 1];
      p += st[t0] + em[b * LL + t0] + et[tl];
    }
    scp[b][jj] = p;
  }
  __syncthreads();
  if (act && jj == 0) {
    float s = 0.f;
#pragma unroll
    for (int i = 0; i < LL; ++i) s += scp[b][i];
    score[b] = s;
  }
  __syncthreads();
  if (tid == 0) {
    float tot = 0.f;
    for (int bb2 = 0; bb2 < BB; ++bb2) tot += score[bb2] - logz[bb2];
    out[0] = -tot / (float)BB;
  }
}

// =====================================================================
extern "C" void kernel_launch(void* const* d_in, const int* in_sizes, int n_in,
                              void* d_out, int out_size, void* d_ws, size_t ws_size,
                              hipStream_t stream) {
  (void)in_sizes; (void)n_in; (void)out_size; (void)ws_size;

  const int* ids     = (const int*)d_in[0];
  const int* labels  = (const int*)d_in[1];
  /* d_in[2] = mask: all-ones in this problem — treated as 1 */
  const float* emb   = (const float*)d_in[3];
  const float* wih_f = (const float*)d_in[4];
  const float* whh_f = (const float*)d_in[5];
  const float* bih_f = (const float*)d_in[6];
  const float* bhh_f = (const float*)d_in[7];
  const float* wih_b = (const float*)d_in[8];
  const float* whh_b = (const float*)d_in[9];
  const float* bih_b = (const float*)d_in[10];
  const float* bhh_b = (const float*)d_in[11];
  const float* wcls  = (const float*)d_in[12];
  const float* bcls  = (const float*)d_in[13];
  const float* st    = (const float*)d_in[14];
  const float* et    = (const float*)d_in[15];
  const float* tr    = (const float*)d_in[16];

  char* ws = (char*)d_ws;
  size_t off = 0;
  auto carve = [&](size_t bytes) -> void* {
    void* p = ws + off;
    off += (bytes + 255) & ~(size_t)255;
    return p;
  };
  u16* xgf   = (u16*)carve((size_t)TT * BB * G4 * sizeof(u16));     // 33.5 MB
  u16* xgb   = (u16*)carve((size_t)TT * BB * G4 * sizeof(u16));     // 33.5 MB
  u32* wreg  = (u32*)carve((size_t)2 * JS * 128 * 256 * sizeof(u32)); // 4.2 MB
  u32* hsf32 = (u32*)carve((size_t)TT * BB * 256 * sizeof(u32));    // 8.4 MB
  u32* hsb32 = (u32*)carve((size_t)TT * BB * 256 * sizeof(u32));    // 8.4 MB
  float* em  = (float*)carve((size_t)TT * BB * LL * sizeof(float)); // 0.56 MB
  u32* hx    = (u32*)carve((size_t)2 * BGN * BGS * 256 * sizeof(u32)); // 64 KB
  u32* flags = (u32*)carve((size_t)2 * BGN * JS * sizeof(u32));     // 1 KB

  hipLaunchKernelGGL(k_zero, dim3(64), dim3(256), 0, stream, hx, flags);

  hipLaunchKernelGGL(k_pack2, dim3(4096), dim3(256), 0, stream,
                     whh_f, whh_b, wreg);

  hipLaunchKernelGGL(k_input_gemm, dim3(64 * 32), dim3(256), 0, stream,
                     ids, emb, wih_f, wih_b, bih_f, bhh_f, bih_b, bhh_b, xgf, xgb);

  {
    void* args[] = {(void*)&xgf, (void*)&xgb, (void*)&wreg,
                    (void*)&hx, (void*)&flags, (void*)&hsf32, (void*)&hsb32};
    hipLaunchCooperativeKernel((void*)k_lstm3, dim3(256), dim3(256), args, 0, stream);
  }

  hipLaunchKernelGGL(k_cls, dim3(TT * BB), dim3(128), 0, stream,
                     hsf32, hsb32, wcls, bcls, em);

  hipLaunchKernelGGL(k_crf, dim3(1), dim3(576), 0, stream,
                     em, labels, st, et, tr, (float*)d_out);
}

// Round 5
// 1748.096 us; speedup vs baseline: 9.5735x; 1.4307x over previous
//
#include <hip/hip_runtime.h>

#define TT 256
#define BB 32
#define HH 512
#define EE 300
#define LL 17
#define G4 2048  /* 4*H */

#define JS 16   /* j-split blocks per (dir,batch-group) */
#define BGN 8   /* batch groups */
#define BGS 4   /* batches per group */
#define NGRP (2 * BGN)   /* 16 groups */

using u16 = unsigned short;
using u32 = unsigned int;
using u64 = unsigned long long;

// ---- bf16 helpers (RNE) ----
__device__ __forceinline__ u32 f2bf(float f) {
  u32 u = __float_as_uint(f);
  return (u + 0x7FFFu + ((u >> 16) & 1u)) >> 16;
}
__device__ __forceinline__ float bfbits2f(u32 lo) { return __uint_as_float(lo << 16); }
__device__ __forceinline__ float bflo(u32 p) { return __uint_as_float(p << 16); }
__device__ __forceinline__ float bfhi(u32 p) { return __uint_as_float(p & 0xFFFF0000u); }

// ---- f16 helpers ----
__device__ __forceinline__ u32 pkf16(float a, float b) {
  u16 lo = __builtin_bit_cast(u16, (_Float16)a);
  u16 hi = __builtin_bit_cast(u16, (_Float16)b);
  return (u32)lo | ((u32)hi << 16);
}
__device__ __forceinline__ float f16lo(u32 p) {
  return (float)__builtin_bit_cast(_Float16, (u16)(p & 0xFFFFu));
}
__device__ __forceinline__ float f16hi(u32 p) {
  return (float)__builtin_bit_cast(_Float16, (u16)(p >> 16));
}

#if __has_builtin(__builtin_amdgcn_fdot2)
using h2v = _Float16 __attribute__((ext_vector_type(2)));
__device__ __forceinline__ float dot2p(u32 w, u32 h, float acc) {
  return __builtin_amdgcn_fdot2(__builtin_bit_cast(h2v, w),
                                __builtin_bit_cast(h2v, h), acc, false);
}
#else
__device__ __forceinline__ float dot2p(u32 w, u32 h, float acc) {
  return fmaf(f16hi(w), f16hi(h), fmaf(f16lo(w), f16lo(h), acc));
}
#endif

#define RX __ATOMIC_RELAXED
#define SCA __HIP_MEMORY_SCOPE_AGENT

// =====================================================================
// Kernel Z: zero the tagged h-exchange buffer (every call -> graph replays
// are deterministic).  hx64: [2 parity][NGRP][1024] u64.
// =====================================================================
__global__ __launch_bounds__(256) void k_zero(u64* __restrict__ hx64) {
  int i = blockIdx.x * 256 + threadIdx.x;
  if (i < 2 * NGRP * 1024) hx64[i] = 0ull;
}

// =====================================================================
// Kernel P: pack w_hh fp32 -> f16 pairs, thread-contiguous layout for
// k_lstm4: wreg[((dir*JS+js)*256 + tid)*128 + i] = W[row][kh*256+2i..+1]
// where tid=(kh<<7)|gl, row(gl,js) = (gl>>5)*512 + js*32 + (gl&31).
// =====================================================================
__global__ __launch_bounds__(256) void k_pack2(
    const float* __restrict__ whhf, const float* __restrict__ whhb,
    u32* __restrict__ wreg)
{
  int idx = blockIdx.x * 256 + threadIdx.x;  // 2*16*256*128 = 1,048,576
  int i = idx & 127;
  int tid2 = (idx >> 7) & 255;
  int js = (idx >> 15) & 15;
  int dir = idx >> 19;
  int gl = tid2 & 127, kh = tid2 >> 7;
  int grow = (gl >> 5) * 512 + js * 32 + (gl & 31);
  int k = kh * 256 + 2 * i;
  const float* w = (dir ? whhb : whhf) + (long)grow * HH + k;
  wreg[idx] = pkf16(w[0], w[1]);
}

// =====================================================================
// Kernel A: embedding gather + input projection for BOTH directions.
// xg[tk][g] = dot(emb[ids[tk]], w_ih[g]) + b_ih[g] + b_hh[g], stored bf16.
// =====================================================================
__global__ __launch_bounds__(256) void k_input_gemm(
    const int* __restrict__ ids, const float* __restrict__ emb,
    const float* __restrict__ wih_f, const float* __restrict__ wih_b,
    const float* __restrict__ bih_f, const float* __restrict__ bhh_f,
    const float* __restrict__ bih_b, const float* __restrict__ bhh_b,
    u16* __restrict__ xgf, u16* __restrict__ xgb)
{
  __shared__ float xs[30][132];
  __shared__ float wsd[30][132];
  __shared__ int idl[128];

  const int tid = threadIdx.x;
  const int mb = blockIdx.x & 63;
  const int nb = blockIdx.x >> 6;
  const int m0 = mb * 128;
  const int n0 = nb * 128;
  const int dir = n0 >> 11;
  const int gl0 = n0 & 2047;
  const float* __restrict__ wih = dir ? wih_b : wih_f;

  if (tid < 128) {
    int tk = m0 + tid;
    idl[tid] = ids[(tk & 31) * TT + (tk >> 5)];
  }
  __syncthreads();

  float acc[8][8];
#pragma unroll
  for (int i = 0; i < 8; ++i)
#pragma unroll
    for (int j = 0; j < 8; ++j) acc[i][j] = 0.f;

  const int tm = tid >> 4, tn = tid & 15;

  for (int e0 = 0; e0 < EE; e0 += 30) {
    for (int idx = tid; idx < 128 * 30; idx += 256) {
      int r = idx / 30, c = idx - r * 30;
      xs[c][r] = emb[(long)idl[r] * EE + (e0 + c)];
    }
    for (int idx = tid; idx < 128 * 30; idx += 256) {
      int r = idx / 30, c = idx - r * 30;
      wsd[c][r] = wih[(long)(gl0 + r) * EE + (e0 + c)];
    }
    __syncthreads();
#pragma unroll 2
    for (int kk = 0; kk < 30; ++kk) {
      float xv[8], wv[8];
      *(float4*)&xv[0] = *(const float4*)&xs[kk][tm * 8];
      *(float4*)&xv[4] = *(const float4*)&xs[kk][tm * 8 + 4];
      *(float4*)&wv[0] = *(const float4*)&wsd[kk][tn * 8];
      *(float4*)&wv[4] = *(const float4*)&wsd[kk][tn * 8 + 4];
#pragma unroll
      for (int i = 0; i < 8; ++i)
#pragma unroll
        for (int j = 0; j < 8; ++j)
          acc[i][j] = fmaf(xv[i], wv[j], acc[i][j]);
    }
    __syncthreads();
  }

  const float* __restrict__ bih = dir ? bih_b : bih_f;
  const float* __restrict__ bhh = dir ? bhh_b : bhh_f;
  u16* __restrict__ xg = dir ? xgb : xgf;
  const int gbase = gl0 + tn * 8;
  float bias[8];
#pragma unroll
  for (int j = 0; j < 8; ++j) bias[j] = bih[gbase + j] + bhh[gbase + j];
#pragma unroll
  for (int i = 0; i < 8; ++i) {
    int tk = m0 + tm * 8 + i;
    u32 pk[4];
#pragma unroll
    for (int jp = 0; jp < 4; ++jp) {
      u32 lo = f2bf(acc[i][2 * jp] + bias[2 * jp]);
      u32 hi = f2bf(acc[i][2 * jp + 1] + bias[2 * jp + 1]);
      pk[jp] = lo | (hi << 16);
    }
    *(uint4*)&xg[(long)tk * G4 + gbase] = make_uint4(pk[0], pk[1], pk[2], pk[3]);
  }
}

// =====================================================================
// Kernel B: BiLSTM recurrence — VGPR-pinned weights + tagged-word exchange.
// 256 blocks = 2 dir x 8 bg x 16 js, 256 threads, cooperative.
// Thread (gl,kh) holds its 128 u32 W f16-pairs pinned in VGPRs (asm).
// Exchange: each h-pair published as one 64-bit word (tag<<32 | pair),
// double-buffered by step parity; consumers poll exactly their 4 words.
// No flags, no fences — atomicity of the u64 carries readiness + data.
// =====================================================================
__global__ __launch_bounds__(256, 1) void k_lstm4(
    const u16* __restrict__ xgf, const u16* __restrict__ xgb,
    const u32* __restrict__ wreg,
    u64* __restrict__ hx64,
    u32* __restrict__ hsf32, u32* __restrict__ hsb32)
{
  __shared__ uint4 h4[256];            // h pairs x 4 batches
  __shared__ float y_sh[2][4][128];    // [khalf][batch][g_local]

  const int tid = threadIdx.x;
  const int bx = blockIdx.x;
  const int dir = bx >> 7;
  const int rem = bx & 127;
  const int bg = rem >> 4;
  const int js = rem & 15;
  const int grp = dir * BGN + bg;

  const u16* __restrict__ xg = dir ? xgb : xgf;
  u32* __restrict__ hs32 = dir ? hsb32 : hsf32;

  const int gl = tid & 127, kh = tid >> 7;
  const int jl = tid & 31, bl = (tid >> 5) & 3;

  // ---- one-time load of persistent weights, pinned into VGPRs ----
  uint4 w4[32];
  {
    const uint4* wp4 = (const uint4*)wreg + ((long)(dir * JS + js) * 256 + tid) * 32;
#pragma unroll
    for (int i = 0; i < 32; ++i) w4[i] = wp4[i];
#pragma unroll
    for (int i = 0; i < 32; ++i)
      asm volatile("" : "+v"(w4[i].x), "+v"(w4[i].y), "+v"(w4[i].z), "+v"(w4[i].w));
  }

  float c_state = 0.f;

  for (int s = 0; s < TT; ++s) {
    const int tok = dir ? (TT - 1 - s) : s;

    // ---- issue xg loads early (independent of h) ----
    u32 xq0 = 0, xq1 = 0, xq2 = 0, xq3 = 0;
    if (tid < 128) {
      const u16* xb = xg + ((long)(tok * BB + bg * BGS + bl) << 11) + js * 32 + jl;
      xq0 = xb[0]; xq1 = xb[512]; xq2 = xb[1024]; xq3 = xb[1536];
    }

    // ---- acquire previous h: poll own 4 tagged words ----
    if (s == 0) {
      h4[tid] = make_uint4(0u, 0u, 0u, 0u);
    } else {
      const u64* hp = hx64 + ((long)(((s - 1) & 1) * NGRP + grp) << 10);
      const u32 want = (u32)s;
      u64 v0, v1, v2, v3;
      for (;;) {
        v0 = __hip_atomic_load(hp + tid, RX, SCA);
        v1 = __hip_atomic_load(hp + 256 + tid, RX, SCA);
        v2 = __hip_atomic_load(hp + 512 + tid, RX, SCA);
        v3 = __hip_atomic_load(hp + 768 + tid, RX, SCA);
        if ((((u32)(v0 >> 32) == want) & ((u32)(v1 >> 32) == want) &
             ((u32)(v2 >> 32) == want) & ((u32)(v3 >> 32) == want)))
          break;
        __builtin_amdgcn_s_sleep(1);
      }
      h4[tid] = make_uint4((u32)v0, (u32)v1, (u32)v2, (u32)v3);
    }
    __syncthreads();

    // ---- matvec over this thread's k-half (weights in VGPRs) ----
    float a0 = 0.f, a1 = 0.f, a2 = 0.f, a3 = 0.f;
    {
      const uint4* hb = h4 + kh * 128;
#pragma unroll
      for (int i = 0; i < 32; ++i) {
        uint4 w = w4[i];
        uint4 hq0 = hb[4 * i + 0];
        uint4 hq1 = hb[4 * i + 1];
        uint4 hq2 = hb[4 * i + 2];
        uint4 hq3 = hb[4 * i + 3];
        a0 = dot2p(w.x, hq0.x, a0); a1 = dot2p(w.x, hq0.y, a1);
        a2 = dot2p(w.x, hq0.z, a2); a3 = dot2p(w.x, hq0.w, a3);
        a0 = dot2p(w.y, hq1.x, a0); a1 = dot2p(w.y, hq1.y, a1);
        a2 = dot2p(w.y, hq1.z, a2); a3 = dot2p(w.y, hq1.w, a3);
        a0 = dot2p(w.z, hq2.x, a0); a1 = dot2p(w.z, hq2.y, a1);
        a2 = dot2p(w.z, hq2.z, a2); a3 = dot2p(w.z, hq2.w, a3);
        a0 = dot2p(w.w, hq3.x, a0); a1 = dot2p(w.w, hq3.y, a1);
        a2 = dot2p(w.w, hq3.z, a2); a3 = dot2p(w.w, hq3.w, a3);
      }
    }
    y_sh[kh][0][gl] = a0;
    y_sh[kh][1][gl] = a1;
    y_sh[kh][2][gl] = a2;
    y_sh[kh][3][gl] = a3;
    __syncthreads();

    // ---- gate update: thread (jl, bl), tid<128 ----
    float hv = 0.f;
    if (tid < 128) {
      float y0 = y_sh[0][bl][jl]      + y_sh[1][bl][jl]      + bfbits2f(xq0);
      float y1 = y_sh[0][bl][32 + jl] + y_sh[1][bl][32 + jl] + bfbits2f(xq1);
      float y2 = y_sh[0][bl][64 + jl] + y_sh[1][bl][64 + jl] + bfbits2f(xq2);
      float y3 = y_sh[0][bl][96 + jl] + y_sh[1][bl][96 + jl] + bfbits2f(xq3);
      float i_ = 1.f / (1.f + __expf(-y0));
      float f_ = 1.f / (1.f + __expf(-y1));
      float gc = fminf(fmaxf(y2, -15.f), 15.f);
      float eg = __expf(2.f * gc);
      float g_ = (eg - 1.f) / (eg + 1.f);
      float o_ = 1.f / (1.f + __expf(-y3));
      c_state = f_ * c_state + i_ * g_;
      float cc = fminf(fmaxf(c_state, -15.f), 15.f);
      float ec = __expf(2.f * cc);
      float th = (ec - 1.f) / (ec + 1.f);
      hv = o_ * th;
    }
    float hnb = __shfl_down(hv, 1);
    if (tid < 128 && !(jl & 1)) {
      u32 hp32 = pkf16(hv, hnb);
      int jp = js * 16 + (jl >> 1);
      __hip_atomic_store(hs32 + ((long)(tok * BB + bg * BGS + bl) << 8) + jp,
                         hp32, RX, SCA);
      u64 v = ((u64)(u32)(s + 1) << 32) | (u64)hp32;
      __hip_atomic_store(hx64 + ((long)((s & 1) * NGRP + grp) << 10) +
                             bl * 256 + jp,
                         v, RX, SCA);
    }
    // no barrier needed here: h4/y_sh hazards are covered by the two
    // barriers above; the tagged words carry their own readiness.
  }
}

// =====================================================================
// Kernel C: classifier. h inputs are f16-packed u32.
// =====================================================================
__global__ __launch_bounds__(128) void k_cls(
    const u32* __restrict__ hsf32, const u32* __restrict__ hsb32,
    const float* __restrict__ wcls, const float* __restrict__ bcls,
    float* __restrict__ em)
{
  __shared__ float h_l[1024];
  __shared__ float part[17][4];
  const int tk = blockIdx.x;
  const int tid = threadIdx.x;

  {
    uint2 vf = ((const uint2*)(hsf32 + (long)tk * 256))[tid];  // 4 f16
    uint2 vb = ((const uint2*)(hsb32 + (long)tk * 256))[tid];
    h_l[4 * tid + 0] = f16lo(vf.x); h_l[4 * tid + 1] = f16hi(vf.x);
    h_l[4 * tid + 2] = f16lo(vf.y); h_l[4 * tid + 3] = f16hi(vf.y);
    h_l[512 + 4 * tid + 0] = f16lo(vb.x); h_l[512 + 4 * tid + 1] = f16hi(vb.x);
    h_l[512 + 4 * tid + 2] = f16lo(vb.y); h_l[512 + 4 * tid + 3] = f16hi(vb.y);
  }
  __syncthreads();

  if (tid < 68) {
    const int l = tid >> 2, kq = tid & 3;
    const float4* wr = (const float4*)(wcls + (long)l * 1024 + kq * 256);
    const float4* hr = (const float4*)(h_l + kq * 256);
    float sum = 0.f;
#pragma unroll 4
    for (int i = 0; i < 64; ++i) {
      float4 a = hr[i]; float4 w = wr[i];
      sum += a.x * w.x + a.y * w.y + a.z * w.z + a.w * w.w;
    }
    part[l][kq] = sum;
  }
  __syncthreads();
  if (tid < LL) {
    float v = bcls[tid] + part[tid][0] + part[tid][1] + part[tid][2] + part[tid][3];
    int t = tk >> 5, b = tk & 31;
    em[(long)t * (BB * LL) + b * LL + tid] = v;
  }
}

// =====================================================================
// Kernel D: CRF loss (torchcrf semantics, mask == all-ones).
// =====================================================================
__global__ __launch_bounds__(576) void k_crf(
    const float* __restrict__ em, const int* __restrict__ labels,
    const float* __restrict__ st, const float* __restrict__ et,
    const float* __restrict__ trans, float* __restrict__ out)
{
  __shared__ float tr[LL][LL + 1];
  __shared__ float alpha[BB][LL + 1];
  __shared__ float scp[BB][LL + 1];
  __shared__ float logz[BB];
  __shared__ float score[BB];

  const int tid = threadIdx.x;
  if (tid < LL * LL) tr[tid / LL][tid % LL] = trans[tid];
  const int b = tid / LL, jj = tid - b * LL;
  const bool act = tid < BB * LL;

  if (act) alpha[b][jj] = st[jj] + em[b * LL + jj];
  __syncthreads();

  for (int t = 1; t < TT; ++t) {
    float nxt = 0.f;
    if (act) {
      const float* arow = alpha[b];
      float m = -1e30f;
#pragma unroll
      for (int i = 0; i < LL; ++i) m = fmaxf(m, arow[i] + tr[i][jj]);
      float s = 0.f;
#pragma unroll
      for (int i = 0; i < LL; ++i) s += __expf(arow[i] + tr[i][jj] - m);
      nxt = m + __logf(s) + em[(long)t * (BB * LL) + b * LL + jj];
    }
    __syncthreads();
    if (act) alpha[b][jj] = nxt;
    __syncthreads();
  }

  if (act && jj == 0) {
    float m = -1e30f;
#pragma unroll
    for (int i = 0; i < LL; ++i) m = fmaxf(m, alpha[b][i] + et[i]);
    float s = 0.f;
#pragma unroll
    for (int i = 0; i < LL; ++i) s += __expf(alpha[b][i] + et[i] - m);
    logz[b] = m + __logf(s);
  }

  if (act) {
    float p = 0.f;
    for (int t = 1 + jj; t < TT; t += LL) {
      int tp = labels[b * TT + t - 1], tc = labels[b * TT + t];
      p += tr[tp][tc] + em[(long)t * (BB * LL) + b * LL + tc];
    }
    if (jj == 0) {
      int t0 = labels[b * TT], tl = labels[b * TT + TT - 1];
      p += st[t0] + em[b * LL + t0] + et[tl];
    }
    scp[b][jj] = p;
  }
  __syncthreads();
  if (act && jj == 0) {
    float s = 0.f;
#pragma unroll
    for (int i = 0; i < LL; ++i) s += scp[b][i];
    score[b] = s;
  }
  __syncthreads();
  if (tid == 0) {
    float tot = 0.f;
    for (int bb2 = 0; bb2 < BB; ++bb2) tot += score[bb2] - logz[bb2];
    out[0] = -tot / (float)BB;
  }
}

// =====================================================================
extern "C" void kernel_launch(void* const* d_in, const int* in_sizes, int n_in,
                              void* d_out, int out_size, void* d_ws, size_t ws_size,
                              hipStream_t stream) {
  (void)in_sizes; (void)n_in; (void)out_size; (void)ws_size;

  const int* ids     = (const int*)d_in[0];
  const int* labels  = (const int*)d_in[1];
  /* d_in[2] = mask: all-ones in this problem — treated as 1 */
  const float* emb   = (const float*)d_in[3];
  const float* wih_f = (const float*)d_in[4];
  const float* whh_f = (const float*)d_in[5];
  const float* bih_f = (const float*)d_in[6];
  const float* bhh_f = (const float*)d_in[7];
  const float* wih_b = (const float*)d_in[8];
  const float* whh_b = (const float*)d_in[9];
  const float* bih_b = (const float*)d_in[10];
  const float* bhh_b = (const float*)d_in[11];
  const float* wcls  = (const float*)d_in[12];
  const float* bcls  = (const float*)d_in[13];
  const float* st    = (const float*)d_in[14];
  const float* et    = (const float*)d_in[15];
  const float* tr    = (const float*)d_in[16];

  char* ws = (char*)d_ws;
  size_t off = 0;
  auto carve = [&](size_t bytes) -> void* {
    void* p = ws + off;
    off += (bytes + 255) & ~(size_t)255;
    return p;
  };
  u16* xgf   = (u16*)carve((size_t)TT * BB * G4 * sizeof(u16));       // 33.5 MB
  u16* xgb   = (u16*)carve((size_t)TT * BB * G4 * sizeof(u16));       // 33.5 MB
  u32* wreg  = (u32*)carve((size_t)2 * JS * 256 * 128 * sizeof(u32)); // 4.2 MB
  u32* hsf32 = (u32*)carve((size_t)TT * BB * 256 * sizeof(u32));      // 8.4 MB
  u32* hsb32 = (u32*)carve((size_t)TT * BB * 256 * sizeof(u32));      // 8.4 MB
  float* em  = (float*)carve((size_t)TT * BB * LL * sizeof(float));   // 0.56 MB
  u64* hx64  = (u64*)carve((size_t)2 * NGRP * 1024 * sizeof(u64));    // 256 KB

  hipLaunchKernelGGL(k_zero, dim3(128), dim3(256), 0, stream, hx64);

  hipLaunchKernelGGL(k_pack2, dim3(4096), dim3(256), 0, stream,
                     whh_f, whh_b, wreg);

  hipLaunchKernelGGL(k_input_gemm, dim3(64 * 32), dim3(256), 0, stream,
                     ids, emb, wih_f, wih_b, bih_f, bhh_f, bih_b, bhh_b, xgf, xgb);

  {
    void* args[] = {(void*)&xgf, (void*)&xgb, (void*)&wreg,
                    (void*)&hx64, (void*)&hsf32, (void*)&hsb32};
    hipLaunchCooperativeKernel((void*)k_lstm4, dim3(256), dim3(256), args, 0, stream);
  }

  hipLaunchKernelGGL(k_cls, dim3(TT * BB), dim3(128), 0, stream,
                     hsf32, hsb32, wcls, bcls, em);

  hipLaunchKernelGGL(k_crf, dim3(1), dim3(576), 0, stream,
                     em, labels, st, et, tr, (float*)d_out);
}

// Round 6
// 1613.798 us; speedup vs baseline: 10.3701x; 1.0832x over previous
//
#include <hip/hip_runtime.h>

#define TT 256
#define BB 32
#define HH 512
#define EE 300
#define LL 17
#define G4 2048  /* 4*H */

#define JS 16   /* j-split blocks per (dir,batch-group) */
#define BGN 8   /* batch groups */
#define BGS 4   /* batches per group */
#define NGRP (2 * BGN)   /* 16 groups */

#define LSTM_LDS (32 * 256 * 16 + 256 * 16 + 2 * 4 * 128 * 4) /* 139264 B */

using u16 = unsigned short;
using u32 = unsigned int;
using u64 = unsigned long long;

// ---- bf16 helpers (RNE) ----
__device__ __forceinline__ u32 f2bf(float f) {
  u32 u = __float_as_uint(f);
  return (u + 0x7FFFu + ((u >> 16) & 1u)) >> 16;
}
__device__ __forceinline__ float bfbits2f(u32 lo) { return __uint_as_float(lo << 16); }
__device__ __forceinline__ float bflo(u32 p) { return __uint_as_float(p << 16); }
__device__ __forceinline__ float bfhi(u32 p) { return __uint_as_float(p & 0xFFFF0000u); }

// ---- f16 helpers ----
__device__ __forceinline__ u32 pkf16(float a, float b) {
  u16 lo = __builtin_bit_cast(u16, (_Float16)a);
  u16 hi = __builtin_bit_cast(u16, (_Float16)b);
  return (u32)lo | ((u32)hi << 16);
}
__device__ __forceinline__ float f16lo(u32 p) {
  return (float)__builtin_bit_cast(_Float16, (u16)(p & 0xFFFFu));
}
__device__ __forceinline__ float f16hi(u32 p) {
  return (float)__builtin_bit_cast(_Float16, (u16)(p >> 16));
}

#if __has_builtin(__builtin_amdgcn_fdot2)
using h2v = _Float16 __attribute__((ext_vector_type(2)));
__device__ __forceinline__ float dot2p(u32 w, u32 h, float acc) {
  return __builtin_amdgcn_fdot2(__builtin_bit_cast(h2v, w),
                                __builtin_bit_cast(h2v, h), acc, false);
}
#else
__device__ __forceinline__ float dot2p(u32 w, u32 h, float acc) {
  return fmaf(f16hi(w), f16hi(h), fmaf(f16lo(w), f16lo(h), acc));
}
#endif

#define RX __ATOMIC_RELAXED
#define SCA __HIP_MEMORY_SCOPE_AGENT

// =====================================================================
// Kernel Z: zero the tagged h-exchange buffer (every call -> graph replays
// are deterministic).  hx64: [2 parity][NGRP][1024] u64.
// =====================================================================
__global__ __launch_bounds__(256) void k_zero(u64* __restrict__ hx64) {
  int i = blockIdx.x * 256 + threadIdx.x;
  if (i < 2 * NGRP * 1024) hx64[i] = 0ull;
}

// =====================================================================
// Kernel P: pack w_hh fp32 -> f16 pairs in the LDS-staging layout of
// k_lstm5: wreg4[((dir*16+js)*32 + i)*256 + tid] = uint4 of k-pairs
// q=0..3 at row(tid,js), k = 2*(kh*128 + 4i + q), tid=(kh<<7)|gl,
// row = (gl>>5)*512 + js*32 + (gl&31).
// =====================================================================
__global__ __launch_bounds__(256) void k_pack2(
    const float* __restrict__ whhf, const float* __restrict__ whhb,
    uint4* __restrict__ wreg4)
{
  int g = blockIdx.x * 256 + threadIdx.x;  // 2*16*32*256 = 262144
  int tid2 = g & 255;
  int i = (g >> 8) & 31;
  int js = (g >> 13) & 15;
  int dir = g >> 17;
  int gl = tid2 & 127, kh = tid2 >> 7;
  int row = (gl >> 5) * 512 + js * 32 + (gl & 31);
  int bk = 2 * (kh * 128 + 4 * i);
  const float* w = (dir ? whhb : whhf) + (long)row * HH + bk;
  uint4 o;
  o.x = pkf16(w[0], w[1]);
  o.y = pkf16(w[2], w[3]);
  o.z = pkf16(w[4], w[5]);
  o.w = pkf16(w[6], w[7]);
  wreg4[g] = o;
}

// =====================================================================
// Kernel A: embedding gather + input projection for BOTH directions.
// xg[tk][g] = dot(emb[ids[tk]], w_ih[g]) + b_ih[g] + b_hh[g], stored bf16.
// =====================================================================
__global__ __launch_bounds__(256) void k_input_gemm(
    const int* __restrict__ ids, const float* __restrict__ emb,
    const float* __restrict__ wih_f, const float* __restrict__ wih_b,
    const float* __restrict__ bih_f, const float* __restrict__ bhh_f,
    const float* __restrict__ bih_b, const float* __restrict__ bhh_b,
    u16* __restrict__ xgf, u16* __restrict__ xgb)
{
  __shared__ float xs[30][132];
  __shared__ float wsd[30][132];
  __shared__ int idl[128];

  const int tid = threadIdx.x;
  const int mb = blockIdx.x & 63;
  const int nb = blockIdx.x >> 6;
  const int m0 = mb * 128;
  const int n0 = nb * 128;
  const int dir = n0 >> 11;
  const int gl0 = n0 & 2047;
  const float* __restrict__ wih = dir ? wih_b : wih_f;

  if (tid < 128) {
    int tk = m0 + tid;
    idl[tid] = ids[(tk & 31) * TT + (tk >> 5)];
  }
  __syncthreads();

  float acc[8][8];
#pragma unroll
  for (int i = 0; i < 8; ++i)
#pragma unroll
    for (int j = 0; j < 8; ++j) acc[i][j] = 0.f;

  const int tm = tid >> 4, tn = tid & 15;

  for (int e0 = 0; e0 < EE; e0 += 30) {
    for (int idx = tid; idx < 128 * 30; idx += 256) {
      int r = idx / 30, c = idx - r * 30;
      xs[c][r] = emb[(long)idl[r] * EE + (e0 + c)];
    }
    for (int idx = tid; idx < 128 * 30; idx += 256) {
      int r = idx / 30, c = idx - r * 30;
      wsd[c][r] = wih[(long)(gl0 + r) * EE + (e0 + c)];
    }
    __syncthreads();
#pragma unroll 2
    for (int kk = 0; kk < 30; ++kk) {
      float xv[8], wv[8];
      *(float4*)&xv[0] = *(const float4*)&xs[kk][tm * 8];
      *(float4*)&xv[4] = *(const float4*)&xs[kk][tm * 8 + 4];
      *(float4*)&wv[0] = *(const float4*)&wsd[kk][tn * 8];
      *(float4*)&wv[4] = *(const float4*)&wsd[kk][tn * 8 + 4];
#pragma unroll
      for (int i = 0; i < 8; ++i)
#pragma unroll
        for (int j = 0; j < 8; ++j)
          acc[i][j] = fmaf(xv[i], wv[j], acc[i][j]);
    }
    __syncthreads();
  }

  const float* __restrict__ bih = dir ? bih_b : bih_f;
  const float* __restrict__ bhh = dir ? bhh_b : bhh_f;
  u16* __restrict__ xg = dir ? xgb : xgf;
  const int gbase = gl0 + tn * 8;
  float bias[8];
#pragma unroll
  for (int j = 0; j < 8; ++j) bias[j] = bih[gbase + j] + bhh[gbase + j];
#pragma unroll
  for (int i = 0; i < 8; ++i) {
    int tk = m0 + tm * 8 + i;
    u32 pk[4];
#pragma unroll
    for (int jp = 0; jp < 4; ++jp) {
      u32 lo = f2bf(acc[i][2 * jp] + bias[2 * jp]);
      u32 hi = f2bf(acc[i][2 * jp + 1] + bias[2 * jp + 1]);
      pk[jp] = lo | (hi << 16);
    }
    *(uint4*)&xg[(long)tk * G4 + gbase] = make_uint4(pk[0], pk[1], pk[2], pk[3]);
  }
}

// =====================================================================
// Kernel B: BiLSTM recurrence — LDS-resident weights + tagged exchange.
// 256 blocks (cooperative): js = bx>>4 (XCD-local groups under round-robin
// dispatch: group-mates share bx%8), grp = bx&15 -> dir, bg.
// One-time stage: 128 KB f16 weight slice -> LDS, layout [i][tid] uint4 so
// per-step reads are lane-contiguous ds_read_b128 (conflict-free).
// Per step: matvec from LDS (w per-lane, h wave-uniform broadcast),
// gate update (c in regs), tagged u64 h-exchange (parity double-buffered).
// =====================================================================
__global__ __launch_bounds__(256, 1) void k_lstm5(
    const u16* __restrict__ xgf, const u16* __restrict__ xgb,
    const uint4* __restrict__ wreg4,
    u64* __restrict__ hx64,
    u32* __restrict__ hsf32, u32* __restrict__ hsb32)
{
  extern __shared__ char smem[];
  uint4* wlds = (uint4*)smem;                       // [32][256] uint4, 128 KB
  uint4* h4 = (uint4*)(smem + 32 * 256 * 16);       // [256] uint4, 4 KB
  float* y_sh = (float*)(smem + 32 * 256 * 16 + 256 * 16); // [2][4][128], 4 KB

  const int tid = threadIdx.x;
  const int bx = blockIdx.x;
  const int js = bx >> 4;
  const int grp = bx & 15;
  const int dir = grp >> 3;
  const int bg = grp & 7;

  const u16* __restrict__ xg = dir ? xgb : xgf;
  u32* __restrict__ hs32 = dir ? hsb32 : hsf32;

  const int gl = tid & 127, kh = tid >> 7;
  const int jl = tid & 31, bl = (tid >> 5) & 3;
  (void)gl;

  // ---- one-time stage: weight slice -> LDS (both sides lane-contiguous) ----
  {
    const uint4* wp4 = wreg4 + (long)(dir * JS + js) * 32 * 256;
#pragma unroll
    for (int i = 0; i < 32; ++i) wlds[i * 256 + tid] = wp4[i * 256 + tid];
  }

  float c_state = 0.f;

  for (int s = 0; s < TT; ++s) {
    const int tok = dir ? (TT - 1 - s) : s;

    // ---- issue xg loads early (independent of h) ----
    u32 xq0 = 0, xq1 = 0, xq2 = 0, xq3 = 0;
    if (tid < 128) {
      const u16* xb = xg + ((long)(tok * BB + bg * BGS + bl) << 11) + js * 32 + jl;
      xq0 = xb[0]; xq1 = xb[512]; xq2 = xb[1024]; xq3 = xb[1536];
    }

    // ---- acquire previous h: poll own 4 tagged words ----
    if (s == 0) {
      h4[tid] = make_uint4(0u, 0u, 0u, 0u);
    } else {
      const u64* hp = hx64 + ((long)(((s - 1) & 1) * NGRP + grp) << 10);
      const u32 want = (u32)s;
      u64 v0, v1, v2, v3;
      for (;;) {
        v0 = __hip_atomic_load(hp + tid, RX, SCA);
        v1 = __hip_atomic_load(hp + 256 + tid, RX, SCA);
        v2 = __hip_atomic_load(hp + 512 + tid, RX, SCA);
        v3 = __hip_atomic_load(hp + 768 + tid, RX, SCA);
        if ((((u32)(v0 >> 32) == want) & ((u32)(v1 >> 32) == want) &
             ((u32)(v2 >> 32) == want) & ((u32)(v3 >> 32) == want)))
          break;
        __builtin_amdgcn_s_sleep(1);
      }
      h4[tid] = make_uint4((u32)v0, (u32)v1, (u32)v2, (u32)v3);
    }
    __syncthreads();

    // ---- matvec over this thread's k-half (weights from LDS) ----
    float a0 = 0.f, a1 = 0.f, a2 = 0.f, a3 = 0.f;
    {
      const uint4* hb = h4 + kh * 128;
#pragma unroll
      for (int i = 0; i < 32; ++i) {
        uint4 w = wlds[i * 256 + tid];
        uint4 hq0 = hb[4 * i + 0];
        uint4 hq1 = hb[4 * i + 1];
        uint4 hq2 = hb[4 * i + 2];
        uint4 hq3 = hb[4 * i + 3];
        a0 = dot2p(w.x, hq0.x, a0); a1 = dot2p(w.x, hq0.y, a1);
        a2 = dot2p(w.x, hq0.z, a2); a3 = dot2p(w.x, hq0.w, a3);
        a0 = dot2p(w.y, hq1.x, a0); a1 = dot2p(w.y, hq1.y, a1);
        a2 = dot2p(w.y, hq1.z, a2); a3 = dot2p(w.y, hq1.w, a3);
        a0 = dot2p(w.z, hq2.x, a0); a1 = dot2p(w.z, hq2.y, a1);
        a2 = dot2p(w.z, hq2.z, a2); a3 = dot2p(w.z, hq2.w, a3);
        a0 = dot2p(w.w, hq3.x, a0); a1 = dot2p(w.w, hq3.y, a1);
        a2 = dot2p(w.w, hq3.z, a2); a3 = dot2p(w.w, hq3.w, a3);
      }
    }
    y_sh[kh * 512 + 0 * 128 + gl] = a0;
    y_sh[kh * 512 + 1 * 128 + gl] = a1;
    y_sh[kh * 512 + 2 * 128 + gl] = a2;
    y_sh[kh * 512 + 3 * 128 + gl] = a3;
    __syncthreads();

    // ---- gate update: thread (jl, bl), tid<128 ----
    float hv = 0.f;
    if (tid < 128) {
      float y0 = y_sh[bl * 128 + jl]      + y_sh[512 + bl * 128 + jl]      + bfbits2f(xq0);
      float y1 = y_sh[bl * 128 + 32 + jl] + y_sh[512 + bl * 128 + 32 + jl] + bfbits2f(xq1);
      float y2 = y_sh[bl * 128 + 64 + jl] + y_sh[512 + bl * 128 + 64 + jl] + bfbits2f(xq2);
      float y3 = y_sh[bl * 128 + 96 + jl] + y_sh[512 + bl * 128 + 96 + jl] + bfbits2f(xq3);
      float i_ = 1.f / (1.f + __expf(-y0));
      float f_ = 1.f / (1.f + __expf(-y1));
      float gc = fminf(fmaxf(y2, -15.f), 15.f);
      float eg = __expf(2.f * gc);
      float g_ = (eg - 1.f) / (eg + 1.f);
      float o_ = 1.f / (1.f + __expf(-y3));
      c_state = f_ * c_state + i_ * g_;
      float cc = fminf(fmaxf(c_state, -15.f), 15.f);
      float ec = __expf(2.f * cc);
      float th = (ec - 1.f) / (ec + 1.f);
      hv = o_ * th;
    }
    float hnb = __shfl_down(hv, 1);
    if (tid < 128 && !(jl & 1)) {
      u32 hp32 = pkf16(hv, hnb);
      int jp = js * 16 + (jl >> 1);
      __hip_atomic_store(hs32 + ((long)(tok * BB + bg * BGS + bl) << 8) + jp,
                         hp32, RX, SCA);
      u64 v = ((u64)(u32)(s + 1) << 32) | (u64)hp32;
      __hip_atomic_store(hx64 + ((long)((s & 1) * NGRP + grp) << 10) +
                             bl * 256 + jp,
                         v, RX, SCA);
    }
    // no extra barrier: h4/y_sh hazards are covered by the two barriers
    // above; the tagged words carry their own readiness.
  }
}

// =====================================================================
// Kernel C: classifier. h inputs are f16-packed u32.
// =====================================================================
__global__ __launch_bounds__(128) void k_cls(
    const u32* __restrict__ hsf32, const u32* __restrict__ hsb32,
    const float* __restrict__ wcls, const float* __restrict__ bcls,
    float* __restrict__ em)
{
  __shared__ float h_l[1024];
  __shared__ float part[17][4];
  const int tk = blockIdx.x;
  const int tid = threadIdx.x;

  {
    uint2 vf = ((const uint2*)(hsf32 + (long)tk * 256))[tid];  // 4 f16
    uint2 vb = ((const uint2*)(hsb32 + (long)tk * 256))[tid];
    h_l[4 * tid + 0] = f16lo(vf.x); h_l[4 * tid + 1] = f16hi(vf.x);
    h_l[4 * tid + 2] = f16lo(vf.y); h_l[4 * tid + 3] = f16hi(vf.y);
    h_l[512 + 4 * tid + 0] = f16lo(vb.x); h_l[512 + 4 * tid + 1] = f16hi(vb.x);
    h_l[512 + 4 * tid + 2] = f16lo(vb.y); h_l[512 + 4 * tid + 3] = f16hi(vb.y);
  }
  __syncthreads();

  if (tid < 68) {
    const int l = tid >> 2, kq = tid & 3;
    const float4* wr = (const float4*)(wcls + (long)l * 1024 + kq * 256);
    const float4* hr = (const float4*)(h_l + kq * 256);
    float sum = 0.f;
#pragma unroll 4
    for (int i = 0; i < 64; ++i) {
      float4 a = hr[i]; float4 w = wr[i];
      sum += a.x * w.x + a.y * w.y + a.z * w.z + a.w * w.w;
    }
    part[l][kq] = sum;
  }
  __syncthreads();
  if (tid < LL) {
    float v = bcls[tid] + part[tid][0] + part[tid][1] + part[tid][2] + part[tid][3];
    int t = tk >> 5, b = tk & 31;
    em[(long)t * (BB * LL) + b * LL + tid] = v;
  }
}

// =====================================================================
// Kernel D: CRF loss (torchcrf semantics, mask == all-ones).
// =====================================================================
__global__ __launch_bounds__(576) void k_crf(
    const float* __restrict__ em, const int* __restrict__ labels,
    const float* __restrict__ st, const float* __restrict__ et,
    const float* __restrict__ trans, float* __restrict__ out)
{
  __shared__ float tr[LL][LL + 1];
  __shared__ float alpha[BB][LL + 1];
  __shared__ float scp[BB][LL + 1];
  __shared__ float logz[BB];
  __shared__ float score[BB];

  const int tid = threadIdx.x;
  if (tid < LL * LL) tr[tid / LL][tid % LL] = trans[tid];
  const int b = tid / LL, jj = tid - b * LL;
  const bool act = tid < BB * LL;

  if (act) alpha[b][jj] = st[jj] + em[b * LL + jj];
  __syncthreads();

  for (int t = 1; t < TT; ++t) {
    float nxt = 0.f;
    if (act) {
      const float* arow = alpha[b];
      float m = -1e30f;
#pragma unroll
      for (int i = 0; i < LL; ++i) m = fmaxf(m, arow[i] + tr[i][jj]);
      float s = 0.f;
#pragma unroll
      for (int i = 0; i < LL; ++i) s += __expf(arow[i] + tr[i][jj] - m);
      nxt = m + __logf(s) + em[(long)t * (BB * LL) + b * LL + jj];
    }
    __syncthreads();
    if (act) alpha[b][jj] = nxt;
    __syncthreads();
  }

  if (act && jj == 0) {
    float m = -1e30f;
#pragma unroll
    for (int i = 0; i < LL; ++i) m = fmaxf(m, alpha[b][i] + et[i]);
    float s = 0.f;
#pragma unroll
    for (int i = 0; i < LL; ++i) s += __expf(alpha[b][i] + et[i] - m);
    logz[b] = m + __logf(s);
  }

  if (act) {
    float p = 0.f;
    for (int t = 1 + jj; t < TT; t += LL) {
      int tp = labels[b * TT + t - 1], tc = labels[b * TT + t];
      p += tr[tp][tc] + em[(long)t * (BB * LL) + b * LL + tc];
    }
    if (jj == 0) {
      int t0 = labels[b * TT], tl = labels[b * TT + TT - 1];
      p += st[t0] + em[b * LL + t0] + et[tl];
    }
    scp[b][jj] = p;
  }
  __syncthreads();
  if (act && jj == 0) {
    float s = 0.f;
#pragma unroll
    for (int i = 0; i < LL; ++i) s += scp[b][i];
    score[b] = s;
  }
  __syncthreads();
  if (tid == 0) {
    float tot = 0.f;
    for (int bb2 = 0; bb2 < BB; ++bb2) tot += score[bb2] - logz[bb2];
    out[0] = -tot / (float)BB;
  }
}

// =====================================================================
extern "C" void kernel_launch(void* const* d_in, const int* in_sizes, int n_in,
                              void* d_out, int out_size, void* d_ws, size_t ws_size,
                              hipStream_t stream) {
  (void)in_sizes; (void)n_in; (void)out_size; (void)ws_size;

  const int* ids     = (const int*)d_in[0];
  const int* labels  = (const int*)d_in[1];
  /* d_in[2] = mask: all-ones in this problem — treated as 1 */
  const float* emb   = (const float*)d_in[3];
  const float* wih_f = (const float*)d_in[4];
  const float* whh_f = (const float*)d_in[5];
  const float* bih_f = (const float*)d_in[6];
  const float* bhh_f = (const float*)d_in[7];
  const float* wih_b = (const float*)d_in[8];
  const float* whh_b = (const float*)d_in[9];
  const float* bih_b = (const float*)d_in[10];
  const float* bhh_b = (const float*)d_in[11];
  const float* wcls  = (const float*)d_in[12];
  const float* bcls  = (const float*)d_in[13];
  const float* st    = (const float*)d_in[14];
  const float* et    = (const float*)d_in[15];
  const float* tr    = (const float*)d_in[16];

  char* ws = (char*)d_ws;
  size_t off = 0;
  auto carve = [&](size_t bytes) -> void* {
    void* p = ws + off;
    off += (bytes + 255) & ~(size_t)255;
    return p;
  };
  u16* xgf    = (u16*)carve((size_t)TT * BB * G4 * sizeof(u16));        // 33.5 MB
  u16* xgb    = (u16*)carve((size_t)TT * BB * G4 * sizeof(u16));        // 33.5 MB
  uint4* wreg4 = (uint4*)carve((size_t)2 * JS * 32 * 256 * sizeof(uint4)); // 4.2 MB
  u32* hsf32  = (u32*)carve((size_t)TT * BB * 256 * sizeof(u32));       // 8.4 MB
  u32* hsb32  = (u32*)carve((size_t)TT * BB * 256 * sizeof(u32));       // 8.4 MB
  float* em   = (float*)carve((size_t)TT * BB * LL * sizeof(float));    // 0.56 MB
  u64* hx64   = (u64*)carve((size_t)2 * NGRP * 1024 * sizeof(u64));     // 256 KB

  // allow >64KB dynamic LDS for the persistent-weight kernel (idempotent)
  (void)hipFuncSetAttribute((const void*)k_lstm5,
                            hipFuncAttributeMaxDynamicSharedMemorySize,
                            LSTM_LDS);

  hipLaunchKernelGGL(k_zero, dim3(128), dim3(256), 0, stream, hx64);

  hipLaunchKernelGGL(k_pack2, dim3(1024), dim3(256), 0, stream,
                     whh_f, whh_b, wreg4);

  hipLaunchKernelGGL(k_input_gemm, dim3(64 * 32), dim3(256), 0, stream,
                     ids, emb, wih_f, wih_b, bih_f, bhh_f, bih_b, bhh_b, xgf, xgb);

  {
    void* args[] = {(void*)&xgf, (void*)&xgb, (void*)&wreg4,
                    (void*)&hx64, (void*)&hsf32, (void*)&hsb32};
    hipLaunchCooperativeKernel((void*)k_lstm5, dim3(256), dim3(256), args,
                               LSTM_LDS, stream);
  }

  hipLaunchKernelGGL(k_cls, dim3(TT * BB), dim3(128), 0, stream,
                     hsf32, hsb32, wcls, bcls, em);

  hipLaunchKernelGGL(k_crf, dim3(1), dim3(576), 0, stream,
                     em, labels, st, et, tr, (float*)d_out);
}

// Round 7
// 1613.696 us; speedup vs baseline: 10.3708x; 1.0001x over previous
//
#include <hip/hip_runtime.h>

#define TT 256
#define BB 32
#define HH 512
#define EE 300
#define LL 17
#define G4 2048  /* 4*H */

#define BGN 8    /* batch groups (4 batches each) */
#define NGRP 16  /* dir x bg exchange groups */

#define LSTM_LDS (131072 + 8192 + 4096) /* w(2x64KB) + h4(8KB) + y(4KB) */

using u16 = unsigned short;
using u32 = unsigned int;
using u64 = unsigned long long;

// ---- bf16 helpers (RNE) ----
__device__ __forceinline__ u32 f2bf(float f) {
  u32 u = __float_as_uint(f);
  return (u + 0x7FFFu + ((u >> 16) & 1u)) >> 16;
}
__device__ __forceinline__ float bfbits2f(u32 lo) { return __uint_as_float(lo << 16); }
__device__ __forceinline__ float bflo(u32 p) { return __uint_as_float(p << 16); }
__device__ __forceinline__ float bfhi(u32 p) { return __uint_as_float(p & 0xFFFF0000u); }

// ---- f16 helpers ----
__device__ __forceinline__ u32 pkf16(float a, float b) {
  u16 lo = __builtin_bit_cast(u16, (_Float16)a);
  u16 hi = __builtin_bit_cast(u16, (_Float16)b);
  return (u32)lo | ((u32)hi << 16);
}
__device__ __forceinline__ float f16lo(u32 p) {
  return (float)__builtin_bit_cast(_Float16, (u16)(p & 0xFFFFu));
}
__device__ __forceinline__ float f16hi(u32 p) {
  return (float)__builtin_bit_cast(_Float16, (u16)(p >> 16));
}

#if __has_builtin(__builtin_amdgcn_fdot2)
using h2v = _Float16 __attribute__((ext_vector_type(2)));
__device__ __forceinline__ float dot2p(u32 w, u32 h, float acc) {
  return __builtin_amdgcn_fdot2(__builtin_bit_cast(h2v, w),
                                __builtin_bit_cast(h2v, h), acc, false);
}
#else
__device__ __forceinline__ float dot2p(u32 w, u32 h, float acc) {
  return fmaf(f16hi(w), f16hi(h), fmaf(f16lo(w), f16lo(h), acc));
}
#endif

#define RX __ATOMIC_RELAXED
#define SCA __HIP_MEMORY_SCOPE_AGENT

// =====================================================================
// Kernel Z: zero the tagged h-exchange buffer (every call -> graph
// replays deterministic). hx64: [2 parity][NGRP][1024] u64 = 32768 words.
// =====================================================================
__global__ __launch_bounds__(256) void k_zero(u64* __restrict__ hx64) {
  int i = blockIdx.x * 256 + threadIdx.x;
  if (i < 2 * NGRP * 1024) hx64[i] = 0ull;
}

// =====================================================================
// Kernel P: pack w_hh fp32 -> f16 pairs in k_lstm6's staging layout:
// wpk[((js*2+dir)*16 + i)*256 + tid] = uint4 of k-pairs for
// row(tid,js) = q*512 + js*16 + jl  (r=tid&63, q=r>>4, jl=r&15),
// k = kq*128 + 8i .. +7 (kq = tid>>6).  js in [0,32).
// =====================================================================
__global__ __launch_bounds__(256) void k_pack3(
    const float* __restrict__ whhf, const float* __restrict__ whhb,
    uint4* __restrict__ wpk)
{
  int g = blockIdx.x * 256 + threadIdx.x;   // 32*2*16*256 = 262144
  int tid2 = g & 255;
  int i = (g >> 8) & 15;
  int dir = (g >> 12) & 1;
  int js = g >> 13;
  int r = tid2 & 63, kq = tid2 >> 6;
  int grow = (r >> 4) * 512 + js * 16 + (r & 15);
  int k = kq * 128 + 8 * i;
  const float* w = (dir ? whhb : whhf) + (long)grow * HH + k;
  uint4 o;
  o.x = pkf16(w[0], w[1]);
  o.y = pkf16(w[2], w[3]);
  o.z = pkf16(w[4], w[5]);
  o.w = pkf16(w[6], w[7]);
  wpk[g] = o;
}

// =====================================================================
// Kernel A: embedding gather + input projection for BOTH directions.
// xg[tk][g] = dot(emb[ids[tk]], w_ih[g]) + b_ih[g] + b_hh[g], stored bf16.
// =====================================================================
__global__ __launch_bounds__(256) void k_input_gemm(
    const int* __restrict__ ids, const float* __restrict__ emb,
    const float* __restrict__ wih_f, const float* __restrict__ wih_b,
    const float* __restrict__ bih_f, const float* __restrict__ bhh_f,
    const float* __restrict__ bih_b, const float* __restrict__ bhh_b,
    u16* __restrict__ xgf, u16* __restrict__ xgb)
{
  __shared__ float xs[30][132];
  __shared__ float wsd[30][132];
  __shared__ int idl[128];

  const int tid = threadIdx.x;
  const int mb = blockIdx.x & 63;
  const int nb = blockIdx.x >> 6;
  const int m0 = mb * 128;
  const int n0 = nb * 128;
  const int dir = n0 >> 11;
  const int gl0 = n0 & 2047;
  const float* __restrict__ wih = dir ? wih_b : wih_f;

  if (tid < 128) {
    int tk = m0 + tid;
    idl[tid] = ids[(tk & 31) * TT + (tk >> 5)];
  }
  __syncthreads();

  float acc[8][8];
#pragma unroll
  for (int i = 0; i < 8; ++i)
#pragma unroll
    for (int j = 0; j < 8; ++j) acc[i][j] = 0.f;

  const int tm = tid >> 4, tn = tid & 15;

  for (int e0 = 0; e0 < EE; e0 += 30) {
    for (int idx = tid; idx < 128 * 30; idx += 256) {
      int r = idx / 30, c = idx - r * 30;
      xs[c][r] = emb[(long)idl[r] * EE + (e0 + c)];
    }
    for (int idx = tid; idx < 128 * 30; idx += 256) {
      int r = idx / 30, c = idx - r * 30;
      wsd[c][r] = wih[(long)(gl0 + r) * EE + (e0 + c)];
    }
    __syncthreads();
#pragma unroll 2
    for (int kk = 0; kk < 30; ++kk) {
      float xv[8], wv[8];
      *(float4*)&xv[0] = *(const float4*)&xs[kk][tm * 8];
      *(float4*)&xv[4] = *(const float4*)&xs[kk][tm * 8 + 4];
      *(float4*)&wv[0] = *(const float4*)&wsd[kk][tn * 8];
      *(float4*)&wv[4] = *(const float4*)&wsd[kk][tn * 8 + 4];
#pragma unroll
      for (int i = 0; i < 8; ++i)
#pragma unroll
        for (int j = 0; j < 8; ++j)
          acc[i][j] = fmaf(xv[i], wv[j], acc[i][j]);
    }
    __syncthreads();
  }

  const float* __restrict__ bih = dir ? bih_b : bih_f;
  const float* __restrict__ bhh = dir ? bhh_b : bhh_f;
  u16* __restrict__ xg = dir ? xgb : xgf;
  const int gbase = gl0 + tn * 8;
  float bias[8];
#pragma unroll
  for (int j = 0; j < 8; ++j) bias[j] = bih[gbase + j] + bhh[gbase + j];
#pragma unroll
  for (int i = 0; i < 8; ++i) {
    int tk = m0 + tm * 8 + i;
    u32 pk[4];
#pragma unroll
    for (int jp = 0; jp < 4; ++jp) {
      u32 lo = f2bf(acc[i][2 * jp] + bias[2 * jp]);
      u32 hi = f2bf(acc[i][2 * jp + 1] + bias[2 * jp + 1]);
      pk[jp] = lo | (hi << 16);
    }
    *(uint4*)&xg[(long)tk * G4 + gbase] = make_uint4(pk[0], pk[1], pk[2], pk[3]);
  }
}

// =====================================================================
// Kernel B: BiLSTM recurrence — dual-direction per block (latency hiding).
// 256 blocks = 8 bg x 32 js, 256 threads, cooperative, 1 block/CU.
// Block owns BOTH dirs of (bg, 16 hidden units): while one dir's h is in
// flight through the exchange, the other dir's matvec runs. Weights for
// both dirs LDS-resident (2 x 64 KB). Matvec: thread (r=tid&63, kq=tid>>6),
// wave = one kq -> h reads wave-uniform (broadcast), w reads lane-contig.
// Exchange: tagged u64 words (tag<<32|f16pair), parity double-buffered.
// =====================================================================
__global__ __launch_bounds__(256, 1) void k_lstm6(
    const u16* __restrict__ xgf, const u16* __restrict__ xgb,
    const uint4* __restrict__ wpk,
    u64* __restrict__ hx64,
    u32* __restrict__ hsf32, u32* __restrict__ hsb32)
{
  extern __shared__ char smem[];
  uint4* wlds = (uint4*)smem;                      // [2][16][256] uint4
  uint4* h4 = (uint4*)(smem + 131072);             // [2][256] uint4
  float* y_sh = (float*)(smem + 131072 + 8192);    // [4 kq][4 b][64 r]

  const int tid = threadIdx.x;
  const int bx = blockIdx.x;
  const int bg = bx & 7;           // same-XCD exchange partners (bx%8)
  const int js = bx >> 3;          // 0..31, 16 hidden units

  const int r = tid & 63, kq = tid >> 6;
  const int jl = tid & 15, bl = (tid >> 4) & 3;    // update mapping, tid<64

  // ---- stage both dirs' weight slices into LDS (lane-contiguous) ----
  {
    const uint4* src = wpk + (long)js * 2 * 4096;
#pragma unroll
    for (int v = 0; v < 32; ++v) wlds[v * 256 + tid] = src[v * 256 + tid];
  }

  float c0 = 0.f, c1 = 0.f;

  for (int s = 0; s < TT; ++s) {
    const int tok0 = s, tok1 = TT - 1 - s;

    // ---- issue xg loads for both dirs early ----
    u32 xa[4], xb_[4];
    if (tid < 64) {
      const u16* p0 = xgf + ((long)(tok0 * BB + bg * 4 + bl) << 11) + js * 16 + jl;
      xa[0] = p0[0]; xa[1] = p0[512]; xa[2] = p0[1024]; xa[3] = p0[1536];
      const u16* p1 = xgb + ((long)(tok1 * BB + bg * 4 + bl) << 11) + js * 16 + jl;
      xb_[0] = p1[0]; xb_[1] = p1[512]; xb_[2] = p1[1024]; xb_[3] = p1[1536];
    }

    // ================= dir 0 =================
    if (s == 0) {
      h4[tid] = make_uint4(0u, 0u, 0u, 0u);
    } else {
      const u64* hp = hx64 + ((long)(((s - 1) & 1) * NGRP + bg) << 10);
      const u32 want = (u32)s;
      u64 v0, v1, v2, v3;
      for (;;) {
        v0 = __hip_atomic_load(hp + tid, RX, SCA);
        v1 = __hip_atomic_load(hp + 256 + tid, RX, SCA);
        v2 = __hip_atomic_load(hp + 512 + tid, RX, SCA);
        v3 = __hip_atomic_load(hp + 768 + tid, RX, SCA);
        if ((((u32)(v0 >> 32) == want) & ((u32)(v1 >> 32) == want) &
             ((u32)(v2 >> 32) == want) & ((u32)(v3 >> 32) == want)))
          break;
        __builtin_amdgcn_s_sleep(1);
      }
      h4[tid] = make_uint4((u32)v0, (u32)v1, (u32)v2, (u32)v3);
    }
    __syncthreads();

    {
      float a0 = 0.f, a1 = 0.f, a2 = 0.f, a3 = 0.f;
      const uint4* wd = wlds;
      const uint4* hd = h4 + kq * 64;
#pragma unroll
      for (int i = 0; i < 16; ++i) {
        uint4 w = wd[i * 256 + tid];
        uint4 hq0 = hd[4 * i + 0];
        uint4 hq1 = hd[4 * i + 1];
        uint4 hq2 = hd[4 * i + 2];
        uint4 hq3 = hd[4 * i + 3];
        a0 = dot2p(w.x, hq0.x, a0); a1 = dot2p(w.x, hq0.y, a1);
        a2 = dot2p(w.x, hq0.z, a2); a3 = dot2p(w.x, hq0.w, a3);
        a0 = dot2p(w.y, hq1.x, a0); a1 = dot2p(w.y, hq1.y, a1);
        a2 = dot2p(w.y, hq1.z, a2); a3 = dot2p(w.y, hq1.w, a3);
        a0 = dot2p(w.z, hq2.x, a0); a1 = dot2p(w.z, hq2.y, a1);
        a2 = dot2p(w.z, hq2.z, a2); a3 = dot2p(w.z, hq2.w, a3);
        a0 = dot2p(w.w, hq3.x, a0); a1 = dot2p(w.w, hq3.y, a1);
        a2 = dot2p(w.w, hq3.z, a2); a3 = dot2p(w.w, hq3.w, a3);
      }
      y_sh[(kq * 4 + 0) * 64 + r] = a0;
      y_sh[(kq * 4 + 1) * 64 + r] = a1;
      y_sh[(kq * 4 + 2) * 64 + r] = a2;
      y_sh[(kq * 4 + 3) * 64 + r] = a3;
    }
    __syncthreads();

    {
      float hv = 0.f;
      if (tid < 64) {
        float yv[4];
#pragma unroll
        for (int q = 0; q < 4; ++q) {
          float sum = bfbits2f(xa[q]);
#pragma unroll
          for (int k2 = 0; k2 < 4; ++k2)
            sum += y_sh[(k2 * 4 + bl) * 64 + q * 16 + jl];
          yv[q] = sum;
        }
        float i_ = 1.f / (1.f + __expf(-yv[0]));
        float f_ = 1.f / (1.f + __expf(-yv[1]));
        float gc = fminf(fmaxf(yv[2], -15.f), 15.f);
        float eg = __expf(2.f * gc);
        float g_ = (eg - 1.f) / (eg + 1.f);
        float o_ = 1.f / (1.f + __expf(-yv[3]));
        c0 = f_ * c0 + i_ * g_;
        float cc = fminf(fmaxf(c0, -15.f), 15.f);
        float ec = __expf(2.f * cc);
        hv = o_ * (ec - 1.f) / (ec + 1.f);
      }
      float hnb = __shfl_down(hv, 1);
      if (tid < 64 && !(jl & 1)) {
        u32 hp32 = pkf16(hv, hnb);
        int jp = js * 8 + (jl >> 1);
        __hip_atomic_store(hsf32 + ((long)(tok0 * BB + bg * 4 + bl) << 8) + jp,
                           hp32, RX, SCA);
        u64 v = ((u64)(u32)(s + 1) << 32) | (u64)hp32;
        __hip_atomic_store(hx64 + ((long)((s & 1) * NGRP + bg) << 10) +
                               bl * 256 + jp, v, RX, SCA);
      }
    }

    // ================= dir 1 =================
    if (s == 0) {
      h4[256 + tid] = make_uint4(0u, 0u, 0u, 0u);
    } else {
      const u64* hp = hx64 + ((long)(((s - 1) & 1) * NGRP + 8 + bg) << 10);
      const u32 want = (u32)s;
      u64 v0, v1, v2, v3;
      for (;;) {
        v0 = __hip_atomic_load(hp + tid, RX, SCA);
        v1 = __hip_atomic_load(hp + 256 + tid, RX, SCA);
        v2 = __hip_atomic_load(hp + 512 + tid, RX, SCA);
        v3 = __hip_atomic_load(hp + 768 + tid, RX, SCA);
        if ((((u32)(v0 >> 32) == want) & ((u32)(v1 >> 32) == want) &
             ((u32)(v2 >> 32) == want) & ((u32)(v3 >> 32) == want)))
          break;
        __builtin_amdgcn_s_sleep(1);
      }
      h4[256 + tid] = make_uint4((u32)v0, (u32)v1, (u32)v2, (u32)v3);
    }
    __syncthreads();

    {
      float a0 = 0.f, a1 = 0.f, a2 = 0.f, a3 = 0.f;
      const uint4* wd = wlds + 4096;
      const uint4* hd = h4 + 256 + kq * 64;
#pragma unroll
      for (int i = 0; i < 16; ++i) {
        uint4 w = wd[i * 256 + tid];
        uint4 hq0 = hd[4 * i + 0];
        uint4 hq1 = hd[4 * i + 1];
        uint4 hq2 = hd[4 * i + 2];
        uint4 hq3 = hd[4 * i + 3];
        a0 = dot2p(w.x, hq0.x, a0); a1 = dot2p(w.x, hq0.y, a1);
        a2 = dot2p(w.x, hq0.z, a2); a3 = dot2p(w.x, hq0.w, a3);
        a0 = dot2p(w.y, hq1.x, a0); a1 = dot2p(w.y, hq1.y, a1);
        a2 = dot2p(w.y, hq1.z, a2); a3 = dot2p(w.y, hq1.w, a3);
        a0 = dot2p(w.z, hq2.x, a0); a1 = dot2p(w.z, hq2.y, a1);
        a2 = dot2p(w.z, hq2.z, a2); a3 = dot2p(w.z, hq2.w, a3);
        a0 = dot2p(w.w, hq3.x, a0); a1 = dot2p(w.w, hq3.y, a1);
        a2 = dot2p(w.w, hq3.z, a2); a3 = dot2p(w.w, hq3.w, a3);
      }
      y_sh[(kq * 4 + 0) * 64 + r] = a0;
      y_sh[(kq * 4 + 1) * 64 + r] = a1;
      y_sh[(kq * 4 + 2) * 64 + r] = a2;
      y_sh[(kq * 4 + 3) * 64 + r] = a3;
    }
    __syncthreads();

    {
      float hv = 0.f;
      if (tid < 64) {
        float yv[4];
#pragma unroll
        for (int q = 0; q < 4; ++q) {
          float sum = bfbits2f(xb_[q]);
#pragma unroll
          for (int k2 = 0; k2 < 4; ++k2)
            sum += y_sh[(k2 * 4 + bl) * 64 + q * 16 + jl];
          yv[q] = sum;
        }
        float i_ = 1.f / (1.f + __expf(-yv[0]));
        float f_ = 1.f / (1.f + __expf(-yv[1]));
        float gc = fminf(fmaxf(yv[2], -15.f), 15.f);
        float eg = __expf(2.f * gc);
        float g_ = (eg - 1.f) / (eg + 1.f);
        float o_ = 1.f / (1.f + __expf(-yv[3]));
        c1 = f_ * c1 + i_ * g_;
        float cc = fminf(fmaxf(c1, -15.f), 15.f);
        float ec = __expf(2.f * cc);
        hv = o_ * (ec - 1.f) / (ec + 1.f);
      }
      float hnb = __shfl_down(hv, 1);
      if (tid < 64 && !(jl & 1)) {
        u32 hp32 = pkf16(hv, hnb);
        int jp = js * 8 + (jl >> 1);
        __hip_atomic_store(hsb32 + ((long)(tok1 * BB + bg * 4 + bl) << 8) + jp,
                           hp32, RX, SCA);
        u64 v = ((u64)(u32)(s + 1) << 32) | (u64)hp32;
        __hip_atomic_store(hx64 + ((long)((s & 1) * NGRP + 8 + bg) << 10) +
                               bl * 256 + jp, v, RX, SCA);
      }
    }
  }
}

// =====================================================================
// Kernel C: classifier. h inputs are f16-packed u32.
// =====================================================================
__global__ __launch_bounds__(128) void k_cls(
    const u32* __restrict__ hsf32, const u32* __restrict__ hsb32,
    const float* __restrict__ wcls, const float* __restrict__ bcls,
    float* __restrict__ em)
{
  __shared__ float h_l[1024];
  __shared__ float part[17][4];
  const int tk = blockIdx.x;
  const int tid = threadIdx.x;

  {
    uint2 vf = ((const uint2*)(hsf32 + (long)tk * 256))[tid];  // 4 f16
    uint2 vb = ((const uint2*)(hsb32 + (long)tk * 256))[tid];
    h_l[4 * tid + 0] = f16lo(vf.x); h_l[4 * tid + 1] = f16hi(vf.x);
    h_l[4 * tid + 2] = f16lo(vf.y); h_l[4 * tid + 3] = f16hi(vf.y);
    h_l[512 + 4 * tid + 0] = f16lo(vb.x); h_l[512 + 4 * tid + 1] = f16hi(vb.x);
    h_l[512 + 4 * tid + 2] = f16lo(vb.y); h_l[512 + 4 * tid + 3] = f16hi(vb.y);
  }
  __syncthreads();

  if (tid < 68) {
    const int l = tid >> 2, kq = tid & 3;
    const float4* wr = (const float4*)(wcls + (long)l * 1024 + kq * 256);
    const float4* hr = (const float4*)(h_l + kq * 256);
    float sum = 0.f;
#pragma unroll 4
    for (int i = 0; i < 64; ++i) {
      float4 a = hr[i]; float4 w = wr[i];
      sum += a.x * w.x + a.y * w.y + a.z * w.z + a.w * w.w;
    }
    part[l][kq] = sum;
  }
  __syncthreads();
  if (tid < LL) {
    float v = bcls[tid] + part[tid][0] + part[tid][1] + part[tid][2] + part[tid][3];
    int t = tk >> 5, b = tk & 31;
    em[(long)t * (BB * LL) + b * LL + tid] = v;
  }
}

// =====================================================================
// Kernel D: CRF loss (torchcrf semantics, mask == all-ones).
// =====================================================================
__global__ __launch_bounds__(576) void k_crf(
    const float* __restrict__ em, const int* __restrict__ labels,
    const float* __restrict__ st, const float* __restrict__ et,
    const float* __restrict__ trans, float* __restrict__ out)
{
  __shared__ float tr[LL][LL + 1];
  __shared__ float alpha[BB][LL + 1];
  __shared__ float scp[BB][LL + 1];
  __shared__ float logz[BB];
  __shared__ float score[BB];

  const int tid = threadIdx.x;
  if (tid < LL * LL) tr[tid / LL][tid % LL] = trans[tid];
  const int b = tid / LL, jj = tid - b * LL;
  const bool act = tid < BB * LL;

  if (act) alpha[b][jj] = st[jj] + em[b * LL + jj];
  __syncthreads();

  for (int t = 1; t < TT; ++t) {
    float nxt = 0.f;
    if (act) {
      const float* arow = alpha[b];
      float m = -1e30f;
#pragma unroll
      for (int i = 0; i < LL; ++i) m = fmaxf(m, arow[i] + tr[i][jj]);
      float s = 0.f;
#pragma unroll
      for (int i = 0; i < LL; ++i) s += __expf(arow[i] + tr[i][jj] - m);
      nxt = m + __logf(s) + em[(long)t * (BB * LL) + b * LL + jj];
    }
    __syncthreads();
    if (act) alpha[b][jj] = nxt;
    __syncthreads();
  }

  if (act && jj == 0) {
    float m = -1e30f;
#pragma unroll
    for (int i = 0; i < LL; ++i) m = fmaxf(m, alpha[b][i] + et[i]);
    float s = 0.f;
#pragma unroll
    for (int i = 0; i < LL; ++i) s += __expf(alpha[b][i] + et[i] - m);
    logz[b] = m + __logf(s);
  }

  if (act) {
    float p = 0.f;
    for (int t = 1 + jj; t < TT; t += LL) {
      int tp = labels[b * TT + t - 1], tc = labels[b * TT + t];
      p += tr[tp][tc] + em[(long)t * (BB * LL) + b * LL + tc];
    }
    if (jj == 0) {
      int t0 = labels[b * TT], tl = labels[b * TT + TT - 1];
      p += st[t0] + em[b * LL + t0] + et[tl];
    }
    scp[b][jj] = p;
  }
  __syncthreads();
  if (act && jj == 0) {
    float s = 0.f;
#pragma unroll
    for (int i = 0; i < LL; ++i) s += scp[b][i];
    score[b] = s;
  }
  __syncthreads();
  if (tid == 0) {
    float tot = 0.f;
    for (int bb2 = 0; bb2 < BB; ++bb2) tot += score[bb2] - logz[bb2];
    out[0] = -tot / (float)BB;
  }
}

// =====================================================================
extern "C" void kernel_launch(void* const* d_in, const int* in_sizes, int n_in,
                              void* d_out, int out_size, void* d_ws, size_t ws_size,
                              hipStream_t stream) {
  (void)in_sizes; (void)n_in; (void)out_size; (void)ws_size;

  const int* ids     = (const int*)d_in[0];
  const int* labels  = (const int*)d_in[1];
  /* d_in[2] = mask: all-ones in this problem — treated as 1 */
  const float* emb   = (const float*)d_in[3];
  const float* wih_f = (const float*)d_in[4];
  const float* whh_f = (const float*)d_in[5];
  const float* bih_f = (const float*)d_in[6];
  const float* bhh_f = (const float*)d_in[7];
  const float* wih_b = (const float*)d_in[8];
  const float* whh_b = (const float*)d_in[9];
  const float* bih_b = (const float*)d_in[10];
  const float* bhh_b = (const float*)d_in[11];
  const float* wcls  = (const float*)d_in[12];
  const float* bcls  = (const float*)d_in[13];
  const float* st    = (const float*)d_in[14];
  const float* et    = (const float*)d_in[15];
  const float* tr    = (const float*)d_in[16];

  char* ws = (char*)d_ws;
  size_t off = 0;
  auto carve = [&](size_t bytes) -> void* {
    void* p = ws + off;
    off += (bytes + 255) & ~(size_t)255;
    return p;
  };
  u16* xgf    = (u16*)carve((size_t)TT * BB * G4 * sizeof(u16));        // 33.5 MB
  u16* xgb    = (u16*)carve((size_t)TT * BB * G4 * sizeof(u16));        // 33.5 MB
  uint4* wpk  = (uint4*)carve((size_t)32 * 2 * 16 * 256 * sizeof(uint4)); // 4.2 MB
  u32* hsf32  = (u32*)carve((size_t)TT * BB * 256 * sizeof(u32));       // 8.4 MB
  u32* hsb32  = (u32*)carve((size_t)TT * BB * 256 * sizeof(u32));       // 8.4 MB
  float* em   = (float*)carve((size_t)TT * BB * LL * sizeof(float));    // 0.56 MB
  u64* hx64   = (u64*)carve((size_t)2 * NGRP * 1024 * sizeof(u64));     // 256 KB

  (void)hipFuncSetAttribute((const void*)k_lstm6,
                            hipFuncAttributeMaxDynamicSharedMemorySize,
                            LSTM_LDS);

  hipLaunchKernelGGL(k_zero, dim3(128), dim3(256), 0, stream, hx64);

  hipLaunchKernelGGL(k_pack3, dim3(1024), dim3(256), 0, stream,
                     whh_f, whh_b, wpk);

  hipLaunchKernelGGL(k_input_gemm, dim3(64 * 32), dim3(256), 0, stream,
                     ids, emb, wih_f, wih_b, bih_f, bhh_f, bih_b, bhh_b, xgf, xgb);

  {
    void* args[] = {(void*)&xgf, (void*)&xgb, (void*)&wpk,
                    (void*)&hx64, (void*)&hsf32, (void*)&hsb32};
    hipLaunchCooperativeKernel((void*)k_lstm6, dim3(256), dim3(256), args,
                               LSTM_LDS, stream);
  }

  hipLaunchKernelGGL(k_cls, dim3(TT * BB), dim3(128), 0, stream,
                     hsf32, hsb32, wcls, bcls, em);

  hipLaunchKernelGGL(k_crf, dim3(1), dim3(576), 0, stream,
                     em, labels, st, et, tr, (float*)d_out);
}

// Round 8
// 1502.159 us; speedup vs baseline: 11.1409x; 1.0743x over previous
//
#include <hip/hip_runtime.h>

#define TT 256
#define BB 32
#define HH 512
#define EE 300
#define LL 17
#define G4 2048  /* 4*H */

#define NGRP 16  /* dir x bg exchange groups (8 bg x 4 batches) */

using u16 = unsigned short;
using u32 = unsigned int;
using u64 = unsigned long long;

typedef _Float16 half8 __attribute__((ext_vector_type(8)));
typedef float f32x4 __attribute__((ext_vector_type(4)));

// ---- bf16 helpers (RNE) ----
__device__ __forceinline__ u32 f2bf(float f) {
  u32 u = __float_as_uint(f);
  return (u + 0x7FFFu + ((u >> 16) & 1u)) >> 16;
}
__device__ __forceinline__ float bfbits2f(u32 lo) { return __uint_as_float(lo << 16); }

// ---- f16 helpers ----
__device__ __forceinline__ u32 pkf16(float a, float b) {
  u16 lo = __builtin_bit_cast(u16, (_Float16)a);
  u16 hi = __builtin_bit_cast(u16, (_Float16)b);
  return (u32)lo | ((u32)hi << 16);
}
__device__ __forceinline__ float f16lo(u32 p) {
  return (float)__builtin_bit_cast(_Float16, (u16)(p & 0xFFFFu));
}
__device__ __forceinline__ float f16hi(u32 p) {
  return (float)__builtin_bit_cast(_Float16, (u16)(p >> 16));
}

#define RX __ATOMIC_RELAXED
#define SCA __HIP_MEMORY_SCOPE_AGENT

// =====================================================================
// Kernel Z: zero the tagged h-exchange buffer (every call -> graph
// replays deterministic). hx64: [2 parity][NGRP][1024] u64.
// =====================================================================
__global__ __launch_bounds__(256) void k_zero(u64* __restrict__ hx64) {
  int i = blockIdx.x * 256 + threadIdx.x;
  if (i < 2 * NGRP * 1024) hx64[i] = 0ull;
}

// =====================================================================
// Kernel P: pack w_hh fp32 -> f16 MFMA A-fragments for k_lstm7.
// wpk2 flat index g = dir*131072 + js*4096 + w*1024 + kstep*64 + l,
// lane l: A-row r = l&15 -> jl = 4w + (r>>2), gate = r&3,
//   grow = gate*512 + js*16 + jl;  k0 = kstep*32 + (l>>4)*8.
// uint4 = 8 f16 = whh[grow][k0..k0+7].
// =====================================================================
__global__ __launch_bounds__(256) void k_pack4(
    const float* __restrict__ whhf, const float* __restrict__ whhb,
    uint4* __restrict__ wpk2)
{
  int g = blockIdx.x * 256 + threadIdx.x;   // 262144 total
  int l = g & 63;
  int kstep = (g >> 6) & 15;
  int w = (g >> 10) & 3;
  int js = (g >> 12) & 31;
  int dir = (g >> 17) & 1;
  int r = l & 15;
  int jl = 4 * w + (r >> 2), gate = r & 3;
  int grow = gate * 512 + js * 16 + jl;
  int k0 = kstep * 32 + (l >> 4) * 8;
  const float* wsrc = (dir ? whhb : whhf) + (long)grow * HH + k0;
  uint4 o;
  o.x = pkf16(wsrc[0], wsrc[1]);
  o.y = pkf16(wsrc[2], wsrc[3]);
  o.z = pkf16(wsrc[4], wsrc[5]);
  o.w = pkf16(wsrc[6], wsrc[7]);
  wpk2[g] = o;
}

// =====================================================================
// Kernel A: embedding gather + input projection for BOTH directions.
// xg[tk][g] = dot(emb[ids[tk]], w_ih[g]) + b_ih[g] + b_hh[g], stored bf16.
// (unchanged)
// =====================================================================
__global__ __launch_bounds__(256) void k_input_gemm(
    const int* __restrict__ ids, const float* __restrict__ emb,
    const float* __restrict__ wih_f, const float* __restrict__ wih_b,
    const float* __restrict__ bih_f, const float* __restrict__ bhh_f,
    const float* __restrict__ bih_b, const float* __restrict__ bhh_b,
    u16* __restrict__ xgf, u16* __restrict__ xgb)
{
  __shared__ float xs[30][132];
  __shared__ float wsd[30][132];
  __shared__ int idl[128];

  const int tid = threadIdx.x;
  const int mb = blockIdx.x & 63;
  const int nb = blockIdx.x >> 6;
  const int m0 = mb * 128;
  const int n0 = nb * 128;
  const int dir = n0 >> 11;
  const int gl0 = n0 & 2047;
  const float* __restrict__ wih = dir ? wih_b : wih_f;

  if (tid < 128) {
    int tk = m0 + tid;
    idl[tid] = ids[(tk & 31) * TT + (tk >> 5)];
  }
  __syncthreads();

  float acc[8][8];
#pragma unroll
  for (int i = 0; i < 8; ++i)
#pragma unroll
    for (int j = 0; j < 8; ++j) acc[i][j] = 0.f;

  const int tm = tid >> 4, tn = tid & 15;

  for (int e0 = 0; e0 < EE; e0 += 30) {
    for (int idx = tid; idx < 128 * 30; idx += 256) {
      int r = idx / 30, c = idx - r * 30;
      xs[c][r] = emb[(long)idl[r] * EE + (e0 + c)];
    }
    for (int idx = tid; idx < 128 * 30; idx += 256) {
      int r = idx / 30, c = idx - r * 30;
      wsd[c][r] = wih[(long)(gl0 + r) * EE + (e0 + c)];
    }
    __syncthreads();
#pragma unroll 2
    for (int kk = 0; kk < 30; ++kk) {
      float xv[8], wv[8];
      *(float4*)&xv[0] = *(const float4*)&xs[kk][tm * 8];
      *(float4*)&xv[4] = *(const float4*)&xs[kk][tm * 8 + 4];
      *(float4*)&wv[0] = *(const float4*)&wsd[kk][tn * 8];
      *(float4*)&wv[4] = *(const float4*)&wsd[kk][tn * 8 + 4];
#pragma unroll
      for (int i = 0; i < 8; ++i)
#pragma unroll
        for (int j = 0; j < 8; ++j)
          acc[i][j] = fmaf(xv[i], wv[j], acc[i][j]);
    }
    __syncthreads();
  }

  const float* __restrict__ bih = dir ? bih_b : bih_f;
  const float* __restrict__ bhh = dir ? bhh_b : bhh_f;
  u16* __restrict__ xg = dir ? xgb : xgf;
  const int gbase = gl0 + tn * 8;
  float bias[8];
#pragma unroll
  for (int j = 0; j < 8; ++j) bias[j] = bih[gbase + j] + bhh[gbase + j];
#pragma unroll
  for (int i = 0; i < 8; ++i) {
    int tk = m0 + tm * 8 + i;
    u32 pk[4];
#pragma unroll
    for (int jp = 0; jp < 4; ++jp) {
      u32 lo = f2bf(acc[i][2 * jp] + bias[2 * jp]);
      u32 hi = f2bf(acc[i][2 * jp + 1] + bias[2 * jp + 1]);
      pk[jp] = lo | (hi << 16);
    }
    *(uint4*)&xg[(long)tk * G4 + gbase] = make_uint4(pk[0], pk[1], pk[2], pk[3]);
  }
}

// =====================================================================
// Kernel B: BiLSTM recurrence — MFMA matvec, register A-fragments.
// 256 blocks = 8 bg x 32 js, 256 threads (4 waves), cooperative.
// Wave w = row-tile: 16 gate-rows = hidden jl in {4w..4w+3} x 4 gates,
// row r = (jl&3)*4 + gate  ->  C-frag: lane l (batch=l&15<4, lgrp=jl&3)
// holds all 4 gates (regs) of one (jl, batch): no y exchange at all.
// B = h staged in LDS as fragments: himg[dir][kstep*64+lgrp*16+batch]
// (batches 4..15 zero). Per wave per dir: 16 ds_read_b128 + 16 MFMA.
// Exchange: tagged u64 words, parity double-buffered (k_lstm6 protocol).
// 2 barriers per step.
// =====================================================================
__global__ __launch_bounds__(256, 1) void k_lstm7(
    const u16* __restrict__ xgf, const u16* __restrict__ xgb,
    const uint4* __restrict__ wpk2,
    u64* __restrict__ hx64,
    u32* __restrict__ hsf32, u32* __restrict__ hsb32)
{
  __shared__ uint4 himg[2][1024];   // 32 KB: [dir][kstep*64 + lgrp*16 + b]

  const int tid = threadIdx.x;
  const int bx = blockIdx.x;
  const int bg = bx & 7;           // same-XCD partners under round-robin
  const int js = bx >> 3;          // 0..31 -> 16 hidden units

  const int w = tid >> 6, l = tid & 63;

  // poll/stage mapping: thread -> (kstep, lane-group, batch)
  const int pk = tid >> 4;
  const int plg = (tid >> 2) & 3;
  const int pb = tid & 3;

  // update mapping (from C-frag layout)
  const int ub = l & 15;              // batch, valid < 4
  const int ujl = 4 * w + (l >> 4);   // hidden index in [0,16)
  const bool uvalid = ub < 4;

  // ---- one-time load of A-fragments (weights) into registers ----
  half8 A0[16], A1[16];
  {
    const uint4* p0 = wpk2 + ((long)js << 12) + (w << 10) + l;
    const uint4* p1 = p0 + (1 << 17);
#pragma unroll
    for (int ks = 0; ks < 16; ++ks) {
      A0[ks] = __builtin_bit_cast(half8, p0[ks << 6]);
      A1[ks] = __builtin_bit_cast(half8, p1[ks << 6]);
    }
  }

  // ---- zero h images (batches >=4 stay zero forever) ----
  for (int i = tid; i < 2048; i += 256)
    ((uint4*)himg)[i] = make_uint4(0u, 0u, 0u, 0u);
  __syncthreads();

  float c0 = 0.f, c1 = 0.f;

  for (int s = 0; s < TT; ++s) {
    const int tok0 = s, tok1 = TT - 1 - s;

    // ---- xg loads for both dirs, issued early ----
    u32 xq0[4] = {0, 0, 0, 0}, xq1[4] = {0, 0, 0, 0};
    if (uvalid) {
      const u16* p = xgf + ((long)(tok0 * BB + bg * 4 + ub) << 11) + js * 16 + ujl;
      xq0[0] = p[0]; xq0[1] = p[512]; xq0[2] = p[1024]; xq0[3] = p[1536];
      const u16* q = xgb + ((long)(tok1 * BB + bg * 4 + ub) << 11) + js * 16 + ujl;
      xq1[0] = q[0]; xq1[1] = q[512]; xq1[2] = q[1024]; xq1[3] = q[1536];
    }

    // ================= dir 0 =================
    if (s > 0) {
      const u64* hp = hx64 + ((long)(((s - 1) & 1) * NGRP + bg) << 10) +
                      pb * 256 + pk * 16 + plg * 4;
      const u32 want = (u32)s;
      u64 v0, v1, v2, v3;
      for (;;) {
        v0 = __hip_atomic_load(hp + 0, RX, SCA);
        v1 = __hip_atomic_load(hp + 1, RX, SCA);
        v2 = __hip_atomic_load(hp + 2, RX, SCA);
        v3 = __hip_atomic_load(hp + 3, RX, SCA);
        if ((((u32)(v0 >> 32) == want) & ((u32)(v1 >> 32) == want) &
             ((u32)(v2 >> 32) == want) & ((u32)(v3 >> 32) == want)))
          break;
        __builtin_amdgcn_s_sleep(1);
      }
      himg[0][pk * 64 + plg * 16 + pb] =
          make_uint4((u32)v0, (u32)v1, (u32)v2, (u32)v3);
    }
    __syncthreads();   // barrier 1: himg[0] staged; prev mfma1 done

    f32x4 acc0 = {0.f, 0.f, 0.f, 0.f};
#pragma unroll
    for (int ks = 0; ks < 16; ++ks) {
      half8 B = __builtin_bit_cast(half8, himg[0][ks * 64 + (l >> 4) * 16 + (l & 15)]);
      acc0 = __builtin_amdgcn_mfma_f32_16x16x32_f16(A0[ks], B, acc0, 0, 0, 0);
    }

    {
      float y0 = acc0[0] + bfbits2f(xq0[0]);
      float y1 = acc0[1] + bfbits2f(xq0[1]);
      float y2 = acc0[2] + bfbits2f(xq0[2]);
      float y3 = acc0[3] + bfbits2f(xq0[3]);
      float i_ = 1.f / (1.f + __expf(-y0));
      float f_ = 1.f / (1.f + __expf(-y1));
      float gc = fminf(fmaxf(y2, -15.f), 15.f);
      float eg = __expf(2.f * gc);
      float g_ = (eg - 1.f) / (eg + 1.f);
      float o_ = 1.f / (1.f + __expf(-y3));
      c0 = f_ * c0 + i_ * g_;
      float cc = fminf(fmaxf(c0, -15.f), 15.f);
      float ec = __expf(2.f * cc);
      float hv = o_ * (ec - 1.f) / (ec + 1.f);
      float hnb = __shfl_down(hv, 16);
      if (uvalid && !((l >> 4) & 1)) {
        u32 pr = pkf16(hv, hnb);
        int jp = js * 8 + (ujl >> 1);
        __hip_atomic_store(hsf32 + ((long)(tok0 * BB + bg * 4 + ub) << 8) + jp,
                           pr, RX, SCA);
        u64 v = ((u64)(u32)(s + 1) << 32) | (u64)pr;
        __hip_atomic_store(hx64 + ((long)((s & 1) * NGRP + bg) << 10) +
                               ub * 256 + jp, v, RX, SCA);
      }
    }

    // ================= dir 1 =================
    if (s > 0) {
      const u64* hp = hx64 + ((long)(((s - 1) & 1) * NGRP + 8 + bg) << 10) +
                      pb * 256 + pk * 16 + plg * 4;
      const u32 want = (u32)s;
      u64 v0, v1, v2, v3;
      for (;;) {
        v0 = __hip_atomic_load(hp + 0, RX, SCA);
        v1 = __hip_atomic_load(hp + 1, RX, SCA);
        v2 = __hip_atomic_load(hp + 2, RX, SCA);
        v3 = __hip_atomic_load(hp + 3, RX, SCA);
        if ((((u32)(v0 >> 32) == want) & ((u32)(v1 >> 32) == want) &
             ((u32)(v2 >> 32) == want) & ((u32)(v3 >> 32) == want)))
          break;
        __builtin_amdgcn_s_sleep(1);
      }
      himg[1][pk * 64 + plg * 16 + pb] =
          make_uint4((u32)v0, (u32)v1, (u32)v2, (u32)v3);
    }
    __syncthreads();   // barrier 2: himg[1] staged; this step's mfma0 done

    f32x4 acc1 = {0.f, 0.f, 0.f, 0.f};
#pragma unroll
    for (int ks = 0; ks < 16; ++ks) {
      half8 B = __builtin_bit_cast(half8, himg[1][ks * 64 + (l >> 4) * 16 + (l & 15)]);
      acc1 = __builtin_amdgcn_mfma_f32_16x16x32_f16(A1[ks], B, acc1, 0, 0, 0);
    }

    {
      float y0 = acc1[0] + bfbits2f(xq1[0]);
      float y1 = acc1[1] + bfbits2f(xq1[1]);
      float y2 = acc1[2] + bfbits2f(xq1[2]);
      float y3 = acc1[3] + bfbits2f(xq1[3]);
      float i_ = 1.f / (1.f + __expf(-y0));
      float f_ = 1.f / (1.f + __expf(-y1));
      float gc = fminf(fmaxf(y2, -15.f), 15.f);
      float eg = __expf(2.f * gc);
      float g_ = (eg - 1.f) / (eg + 1.f);
      float o_ = 1.f / (1.f + __expf(-y3));
      c1 = f_ * c1 + i_ * g_;
      float cc = fminf(fmaxf(c1, -15.f), 15.f);
      float ec = __expf(2.f * cc);
      float hv = o_ * (ec - 1.f) / (ec + 1.f);
      float hnb = __shfl_down(hv, 16);
      if (uvalid && !((l >> 4) & 1)) {
        u32 pr = pkf16(hv, hnb);
        int jp = js * 8 + (ujl >> 1);
        __hip_atomic_store(hsb32 + ((long)(tok1 * BB + bg * 4 + ub) << 8) + jp,
                           pr, RX, SCA);
        u64 v = ((u64)(u32)(s + 1) << 32) | (u64)pr;
        __hip_atomic_store(hx64 + ((long)((s & 1) * NGRP + 8 + bg) << 10) +
                               ub * 256 + jp, v, RX, SCA);
      }
    }
  }
}

// =====================================================================
// Kernel C: classifier. h inputs are f16-packed u32. (unchanged)
// =====================================================================
__global__ __launch_bounds__(128) void k_cls(
    const u32* __restrict__ hsf32, const u32* __restrict__ hsb32,
    const float* __restrict__ wcls, const float* __restrict__ bcls,
    float* __restrict__ em)
{
  __shared__ float h_l[1024];
  __shared__ float part[17][4];
  const int tk = blockIdx.x;
  const int tid = threadIdx.x;

  {
    uint2 vf = ((const uint2*)(hsf32 + (long)tk * 256))[tid];
    uint2 vb = ((const uint2*)(hsb32 + (long)tk * 256))[tid];
    h_l[4 * tid + 0] = f16lo(vf.x); h_l[4 * tid + 1] = f16hi(vf.x);
    h_l[4 * tid + 2] = f16lo(vf.y); h_l[4 * tid + 3] = f16hi(vf.y);
    h_l[512 + 4 * tid + 0] = f16lo(vb.x); h_l[512 + 4 * tid + 1] = f16hi(vb.x);
    h_l[512 + 4 * tid + 2] = f16lo(vb.y); h_l[512 + 4 * tid + 3] = f16hi(vb.y);
  }
  __syncthreads();

  if (tid < 68) {
    const int ll = tid >> 2, kq = tid & 3;
    const float4* wr = (const float4*)(wcls + (long)ll * 1024 + kq * 256);
    const float4* hr = (const float4*)(h_l + kq * 256);
    float sum = 0.f;
#pragma unroll 4
    for (int i = 0; i < 64; ++i) {
      float4 a = hr[i]; float4 wv = wr[i];
      sum += a.x * wv.x + a.y * wv.y + a.z * wv.z + a.w * wv.w;
    }
    part[ll][kq] = sum;
  }
  __syncthreads();
  if (tid < LL) {
    float v = bcls[tid] + part[tid][0] + part[tid][1] + part[tid][2] + part[tid][3];
    int t = tk >> 5, b = tk & 31;
    em[(long)t * (BB * LL) + b * LL + tid] = v;
  }
}

// =====================================================================
// Kernel D: CRF loss (torchcrf semantics, mask == all-ones). (unchanged)
// =====================================================================
__global__ __launch_bounds__(576) void k_crf(
    const float* __restrict__ em, const int* __restrict__ labels,
    const float* __restrict__ st, const float* __restrict__ et,
    const float* __restrict__ trans, float* __restrict__ out)
{
  __shared__ float tr[LL][LL + 1];
  __shared__ float alpha[BB][LL + 1];
  __shared__ float scp[BB][LL + 1];
  __shared__ float logz[BB];
  __shared__ float score[BB];

  const int tid = threadIdx.x;
  if (tid < LL * LL) tr[tid / LL][tid % LL] = trans[tid];
  const int b = tid / LL, jj = tid - b * LL;
  const bool act = tid < BB * LL;

  if (act) alpha[b][jj] = st[jj] + em[b * LL + jj];
  __syncthreads();

  for (int t = 1; t < TT; ++t) {
    float nxt = 0.f;
    if (act) {
      const float* arow = alpha[b];
      float m = -1e30f;
#pragma unroll
      for (int i = 0; i < LL; ++i) m = fmaxf(m, arow[i] + tr[i][jj]);
      float s = 0.f;
#pragma unroll
      for (int i = 0; i < LL; ++i) s += __expf(arow[i] + tr[i][jj] - m);
      nxt = m + __logf(s) + em[(long)t * (BB * LL) + b * LL + jj];
    }
    __syncthreads();
    if (act) alpha[b][jj] = nxt;
    __syncthreads();
  }

  if (act && jj == 0) {
    float m = -1e30f;
#pragma unroll
    for (int i = 0; i < LL; ++i) m = fmaxf(m, alpha[b][i] + et[i]);
    float s = 0.f;
#pragma unroll
    for (int i = 0; i < LL; ++i) s += __expf(alpha[b][i] + et[i] - m);
    logz[b] = m + __logf(s);
  }

  if (act) {
    float p = 0.f;
    for (int t = 1 + jj; t < TT; t += LL) {
      int tp = labels[b * TT + t - 1], tc = labels[b * TT + t];
      p += tr[tp][tc] + em[(long)t * (BB * LL) + b * LL + tc];
    }
    if (jj == 0) {
      int t0 = labels[b * TT], tl = labels[b * TT + TT - 1];
      p += st[t0] + em[b * LL + t0] + et[tl];
    }
    scp[b][jj] = p;
  }
  __syncthreads();
  if (act && jj == 0) {
    float s = 0.f;
#pragma unroll
    for (int i = 0; i < LL; ++i) s += scp[b][i];
    score[b] = s;
  }
  __syncthreads();
  if (tid == 0) {
    float tot = 0.f;
    for (int bb2 = 0; bb2 < BB; ++bb2) tot += score[bb2] - logz[bb2];
    out[0] = -tot / (float)BB;
  }
}

// =====================================================================
extern "C" void kernel_launch(void* const* d_in, const int* in_sizes, int n_in,
                              void* d_out, int out_size, void* d_ws, size_t ws_size,
                              hipStream_t stream) {
  (void)in_sizes; (void)n_in; (void)out_size; (void)ws_size;

  const int* ids     = (const int*)d_in[0];
  const int* labels  = (const int*)d_in[1];
  /* d_in[2] = mask: all-ones in this problem — treated as 1 */
  const float* emb   = (const float*)d_in[3];
  const float* wih_f = (const float*)d_in[4];
  const float* whh_f = (const float*)d_in[5];
  const float* bih_f = (const float*)d_in[6];
  const float* bhh_f = (const float*)d_in[7];
  const float* wih_b = (const float*)d_in[8];
  const float* whh_b = (const float*)d_in[9];
  const float* bih_b = (const float*)d_in[10];
  const float* bhh_b = (const float*)d_in[11];
  const float* wcls  = (const float*)d_in[12];
  const float* bcls  = (const float*)d_in[13];
  const float* st    = (const float*)d_in[14];
  const float* et    = (const float*)d_in[15];
  const float* tr    = (const float*)d_in[16];

  char* ws = (char*)d_ws;
  size_t off = 0;
  auto carve = [&](size_t bytes) -> void* {
    void* p = ws + off;
    off += (bytes + 255) & ~(size_t)255;
    return p;
  };
  u16* xgf    = (u16*)carve((size_t)TT * BB * G4 * sizeof(u16));        // 33.5 MB
  u16* xgb    = (u16*)carve((size_t)TT * BB * G4 * sizeof(u16));        // 33.5 MB
  uint4* wpk2 = (uint4*)carve((size_t)2 * 32 * 4 * 16 * 64 * sizeof(uint4)); // 4.2 MB
  u32* hsf32  = (u32*)carve((size_t)TT * BB * 256 * sizeof(u32));       // 8.4 MB
  u32* hsb32  = (u32*)carve((size_t)TT * BB * 256 * sizeof(u32));       // 8.4 MB
  float* em   = (float*)carve((size_t)TT * BB * LL * sizeof(float));    // 0.56 MB
  u64* hx64   = (u64*)carve((size_t)2 * NGRP * 1024 * sizeof(u64));     // 256 KB

  hipLaunchKernelGGL(k_zero, dim3(128), dim3(256), 0, stream, hx64);

  hipLaunchKernelGGL(k_pack4, dim3(1024), dim3(256), 0, stream,
                     whh_f, whh_b, wpk2);

  hipLaunchKernelGGL(k_input_gemm, dim3(64 * 32), dim3(256), 0, stream,
                     ids, emb, wih_f, wih_b, bih_f, bhh_f, bih_b, bhh_b, xgf, xgb);

  {
    void* args[] = {(void*)&xgf, (void*)&xgb, (void*)&wpk2,
                    (void*)&hx64, (void*)&hsf32, (void*)&hsb32};
    hipLaunchCooperativeKernel((void*)k_lstm7, dim3(256), dim3(256), args,
                               0, stream);
  }

  hipLaunchKernelGGL(k_cls, dim3(TT * BB), dim3(128), 0, stream,
                     hsf32, hsb32, wcls, bcls, em);

  hipLaunchKernelGGL(k_crf, dim3(1), dim3(576), 0, stream,
                     em, labels, st, et, tr, (float*)d_out);
}